// Round 1
// baseline (8826.700 us; speedup 1.0000x reference)
//
#include <hip/hip_runtime.h>
#include <hip/hip_bf16.h>
#include <math.h>

#define F_IN 128
#define HD   64    // H*D layer1
#define NH   8
#define DH   8
#define NC   7     // classes

__device__ __forceinline__ void atomAddF(float* p, float v) {
#if __has_builtin(__builtin_amdgcn_is_shared)  // always true on amdgcn; just use unsafeAtomicAdd
    unsafeAtomicAdd(p, v);
#else
    atomicAdd(p, v);
#endif
}

__device__ __forceinline__ float lrelu(float e) { return e >= 0.f ? e : 0.2f * e; }

// ---------------- K1: h1 = x@W1, a_src1/a_dst1 = (h1*att).sum(-1) -------------
__global__ __launch_bounds__(256) void k_gemm1(
    const float* __restrict__ x, const float* __restrict__ W1,
    const float* __restrict__ att_src, const float* __restrict__ att_dst,
    float* __restrict__ h1, float* __restrict__ a_src, float* __restrict__ a_dst,
    int N)
{
    __shared__ float sW[F_IN * HD];      // 32 KB
    __shared__ float sAs[HD], sAd[HD];
    int t = threadIdx.x;
    for (int i = t; i < F_IN * HD; i += 256) sW[i] = W1[i];
    if (t < HD) { sAs[t] = att_src[t]; sAd[t] = att_dst[t]; }
    __syncthreads();

    int lane = t & 63;
    int wave = t >> 6;
    int base = blockIdx.x * 64;

    for (int it = 0; it < 16; ++it) {
        int row = base + it * 4 + wave;
        if (row >= N) continue;
        const float4* xr4 = (const float4*)(x + (size_t)row * F_IN);
        float acc = 0.f;
        #pragma unroll 8
        for (int k4 = 0; k4 < F_IN / 4; ++k4) {
            float4 xv = xr4[k4];
            acc += xv.x * sW[(k4 * 4 + 0) * HD + lane];
            acc += xv.y * sW[(k4 * 4 + 1) * HD + lane];
            acc += xv.z * sW[(k4 * 4 + 2) * HD + lane];
            acc += xv.w * sW[(k4 * 4 + 3) * HD + lane];
        }
        h1[(size_t)row * HD + lane] = acc;
        float vs = acc * sAs[lane];
        float vd = acc * sAd[lane];
        // reduce within 8-lane groups (one head each)
        #pragma unroll
        for (int o = 4; o > 0; o >>= 1) {
            vs += __shfl_down(vs, o, 8);
            vd += __shfl_down(vd, o, 8);
        }
        if ((lane & 7) == 0) {
            int h = lane >> 3;
            a_src[row * NH + h] = vs;
            a_dst[row * NH + h] = vd;
        }
    }
}

// ---------------- K2: denom1[d,h] += exp(lrelu(a_src[s,h]+a_dst[d,h])) --------
__global__ __launch_bounds__(256) void k_denom1(
    const int* __restrict__ src, const int* __restrict__ dst,
    const float* __restrict__ a_src, const float* __restrict__ a_dst,
    float* __restrict__ denom, long E, int N)
{
    long i = (long)blockIdx.x * 256 + threadIdx.x;
    long tot = E + N;
    if (i >= tot) return;
    int s, d;
    if (i < E) { s = src[i]; d = dst[i]; } else { s = d = (int)(i - E); }
    const float4* as = (const float4*)(a_src + (size_t)s * NH);
    const float4* ad = (const float4*)(a_dst + (size_t)d * NH);
    float4 s0 = as[0], s1 = as[1];
    float4 d0 = ad[0], d1 = ad[1];
    float w[NH];
    w[0] = expf(lrelu(s0.x + d0.x)); w[1] = expf(lrelu(s0.y + d0.y));
    w[2] = expf(lrelu(s0.z + d0.z)); w[3] = expf(lrelu(s0.w + d0.w));
    w[4] = expf(lrelu(s1.x + d1.x)); w[5] = expf(lrelu(s1.y + d1.y));
    w[6] = expf(lrelu(s1.z + d1.z)); w[7] = expf(lrelu(s1.w + d1.w));
    float* dp = denom + (size_t)d * NH;
    #pragma unroll
    for (int h = 0; h < NH; ++h) atomAddF(&dp[h], w[h]);
}

// ---------------- K3: agg1[d] += h1[s]*alpha, thread per (edge,head) ----------
__global__ __launch_bounds__(256) void k_agg1(
    const int* __restrict__ src, const int* __restrict__ dst,
    const float* __restrict__ a_src, const float* __restrict__ a_dst,
    const float* __restrict__ denom, const float* __restrict__ h1,
    float* __restrict__ agg, long E, int N)
{
    long gid = (long)blockIdx.x * 256 + threadIdx.x;
    long tot = (E + N) * NH;
    if (gid >= tot) return;
    long i = gid >> 3;
    int h = (int)(gid & 7);
    int s, d;
    if (i < E) { s = src[i]; d = dst[i]; } else { s = d = (int)(i - E); }
    float e = lrelu(a_src[(size_t)s * NH + h] + a_dst[(size_t)d * NH + h]);
    float alpha = expf(e) / (denom[(size_t)d * NH + h] + 1e-16f);
    const float* hs = h1 + (size_t)s * HD + h * DH;
    float* op = agg + (size_t)d * HD + h * DH;
    #pragma unroll
    for (int j = 0; j < DH; ++j) atomAddF(&op[j], hs[j] * alpha);
}

// ------- K4: emb = agg1+b1 (OUT0); x2 = elu(emb); h2 = x2@W2; a_*2 ------------
__global__ __launch_bounds__(256) void k_node2(
    const float* __restrict__ agg1, const float* __restrict__ b1,
    const float* __restrict__ W2, const float* __restrict__ att_s2,
    const float* __restrict__ att_d2, float* __restrict__ emb_out,
    float* __restrict__ h2, float* __restrict__ a_src2, float* __restrict__ a_dst2,
    int N)
{
    __shared__ float sW[HD * NC];   // 448
    __shared__ float sb[HD];
    __shared__ float sas[NC], sad[NC];
    int t = threadIdx.x;
    for (int i = t; i < HD * NC; i += 256) sW[i] = W2[i];
    if (t < HD) sb[t] = b1[t];
    if (t < NC) { sas[t] = att_s2[t]; sad[t] = att_d2[t]; }
    __syncthreads();
    int n = blockIdx.x * 256 + t;
    if (n >= N) return;
    const float* ag = agg1 + (size_t)n * HD;
    float* eo = emb_out + (size_t)n * HD;
    float acc[NC];
    #pragma unroll
    for (int c = 0; c < NC; ++c) acc[c] = 0.f;
    #pragma unroll 8
    for (int k = 0; k < HD; ++k) {
        float v = ag[k] + sb[k];
        eo[k] = v;
        float xv = v > 0.f ? v : expm1f(v);   // jax.nn.elu
        #pragma unroll
        for (int c = 0; c < NC; ++c) acc[c] += xv * sW[k * NC + c];
    }
    float as = 0.f, ad = 0.f;
    float* hp = h2 + (size_t)n * NC;
    #pragma unroll
    for (int c = 0; c < NC; ++c) {
        hp[c] = acc[c];
        as += acc[c] * sas[c];
        ad += acc[c] * sad[c];
    }
    a_src2[n] = as;
    a_dst2[n] = ad;
}

// ---------------- K5: denom2[d] += exp(lrelu(a2[s]+a2[d])) --------------------
__global__ __launch_bounds__(256) void k_denom2(
    const int* __restrict__ src, const int* __restrict__ dst,
    const float* __restrict__ a_src2, const float* __restrict__ a_dst2,
    float* __restrict__ denom2, long E, int N)
{
    long i = (long)blockIdx.x * 256 + threadIdx.x;
    long tot = E + N;
    if (i >= tot) return;
    int s, d;
    if (i < E) { s = src[i]; d = dst[i]; } else { s = d = (int)(i - E); }
    float w = expf(lrelu(a_src2[s] + a_dst2[d]));
    atomAddF(&denom2[d], w);
}

// ---------------- K6: agg2[d] += h2[s]*alpha ----------------------------------
__global__ __launch_bounds__(256) void k_agg2(
    const int* __restrict__ src, const int* __restrict__ dst,
    const float* __restrict__ a_src2, const float* __restrict__ a_dst2,
    const float* __restrict__ denom2, const float* __restrict__ h2,
    float* __restrict__ agg2, long E, int N)
{
    long i = (long)blockIdx.x * 256 + threadIdx.x;
    long tot = E + N;
    if (i >= tot) return;
    int s, d;
    if (i < E) { s = src[i]; d = dst[i]; } else { s = d = (int)(i - E); }
    float e = lrelu(a_src2[s] + a_dst2[d]);
    float alpha = expf(e) / (denom2[d] + 1e-16f);
    const float* hs = h2 + (size_t)s * NC;
    float* op = agg2 + (size_t)d * NC;
    #pragma unroll
    for (int c = 0; c < NC; ++c) atomAddF(&op[c], hs[c] * alpha);
}

// ---------------- K7: log_softmax(agg2 + b2) → OUT1 ---------------------------
__global__ __launch_bounds__(256) void k_final(
    const float* __restrict__ agg2, const float* __restrict__ b2,
    float* __restrict__ out, int N)
{
    int n = blockIdx.x * 256 + threadIdx.x;
    if (n >= N) return;
    const float* ap = agg2 + (size_t)n * NC;
    float l[NC];
    float m = -1e30f;
    #pragma unroll
    for (int c = 0; c < NC; ++c) { l[c] = ap[c] + b2[c]; m = fmaxf(m, l[c]); }
    float sum = 0.f;
    #pragma unroll
    for (int c = 0; c < NC; ++c) sum += expf(l[c] - m);
    float lse = logf(sum);
    float* op = out + (size_t)n * NC;
    #pragma unroll
    for (int c = 0; c < NC; ++c) op[c] = l[c] - m - lse;
}

extern "C" void kernel_launch(void* const* d_in, const int* in_sizes, int n_in,
                              void* d_out, int out_size, void* d_ws, size_t ws_size,
                              hipStream_t stream)
{
    const float* x       = (const float*)d_in[0];
    const int*   ei      = (const int*)d_in[1];
    const float* W1      = (const float*)d_in[2];
    const float* att_s1  = (const float*)d_in[3];
    const float* att_d1  = (const float*)d_in[4];
    const float* b1      = (const float*)d_in[5];
    const float* W2      = (const float*)d_in[6];
    const float* att_s2  = (const float*)d_in[7];
    const float* att_d2  = (const float*)d_in[8];
    const float* b2      = (const float*)d_in[9];

    const int  N = in_sizes[0] / F_IN;
    const long E = (long)in_sizes[1] / 2;
    const int* src = ei;
    const int* dst = ei + E;

    float* ws = (float*)d_ws;
    // zero-initialized accumulator region (one contiguous memset)
    float* agg1   = ws;                              // N*64
    float* denom1 = agg1   + (size_t)N * HD;         // N*8
    float* agg2   = denom1 + (size_t)N * NH;         // N*7
    float* denom2 = agg2   + (size_t)N * NC;         // N
    // non-zeroed scratch
    float* h1     = denom2 + (size_t)N;              // N*64
    float* a_src1 = h1     + (size_t)N * HD;         // N*8
    float* a_dst1 = a_src1 + (size_t)N * NH;         // N*8
    float* h2     = a_dst1 + (size_t)N * NH;         // N*7
    float* a_src2 = h2     + (size_t)N * NC;         // N
    float* a_dst2 = a_src2 + (size_t)N;              // N

    size_t zeroFloats = (size_t)N * (HD + NH + NC + 1);
    hipMemsetAsync(ws, 0, zeroFloats * sizeof(float), stream);

    const long ET = E + N;  // edges incl. self-loops

    dim3 b256(256);
    // Layer 1
    k_gemm1<<<dim3((N + 63) / 64), b256, 0, stream>>>(x, W1, att_s1, att_d1,
                                                      h1, a_src1, a_dst1, N);
    k_denom1<<<dim3((unsigned)((ET + 255) / 256)), b256, 0, stream>>>(
        src, dst, a_src1, a_dst1, denom1, E, N);
    k_agg1<<<dim3((unsigned)((ET * NH + 255) / 256)), b256, 0, stream>>>(
        src, dst, a_src1, a_dst1, denom1, h1, agg1, E, N);

    // emb output + layer-2 prologue
    float* emb = (float*)d_out;                       // N*64
    float* lsm = emb + (size_t)N * HD;                // N*7
    k_node2<<<dim3((N + 255) / 256), b256, 0, stream>>>(
        agg1, b1, W2, att_s2, att_d2, emb, h2, a_src2, a_dst2, N);

    // Layer 2
    k_denom2<<<dim3((unsigned)((ET + 255) / 256)), b256, 0, stream>>>(
        src, dst, a_src2, a_dst2, denom2, E, N);
    k_agg2<<<dim3((unsigned)((ET + 255) / 256)), b256, 0, stream>>>(
        src, dst, a_src2, a_dst2, denom2, h2, agg2, E, N);
    k_final<<<dim3((N + 255) / 256), b256, 0, stream>>>(agg2, b2, lsm, N);
}

// Round 2
// 902.095 us; speedup vs baseline: 9.7847x; 9.7847x over previous
//
#include <hip/hip_runtime.h>
#include <hip/hip_bf16.h>
#include <math.h>

#define F_IN 128
#define HD   64    // H*D layer1
#define NH   8
#define DH   8
#define NC   7     // classes

__device__ __forceinline__ float lrelu(float e) { return e >= 0.f ? e : 0.2f * e; }

// ---------------- K1: h1 = x@W1, a_src1/a_dst1 = (h1*att).sum(-1) -------------
__global__ __launch_bounds__(256) void k_gemm1(
    const float* __restrict__ x, const float* __restrict__ W1,
    const float* __restrict__ att_src, const float* __restrict__ att_dst,
    float* __restrict__ h1, float* __restrict__ a_src, float* __restrict__ a_dst,
    int N)
{
    __shared__ float sW[F_IN * HD];      // 32 KB
    __shared__ float sAs[HD], sAd[HD];
    int t = threadIdx.x;
    for (int i = t; i < F_IN * HD; i += 256) sW[i] = W1[i];
    if (t < HD) { sAs[t] = att_src[t]; sAd[t] = att_dst[t]; }
    __syncthreads();

    int lane = t & 63;
    int wave = t >> 6;
    int base = blockIdx.x * 64;

    for (int it = 0; it < 16; ++it) {
        int row = base + it * 4 + wave;
        if (row >= N) continue;
        const float4* xr4 = (const float4*)(x + (size_t)row * F_IN);
        float acc = 0.f;
        #pragma unroll 8
        for (int k4 = 0; k4 < F_IN / 4; ++k4) {
            float4 xv = xr4[k4];
            acc += xv.x * sW[(k4 * 4 + 0) * HD + lane];
            acc += xv.y * sW[(k4 * 4 + 1) * HD + lane];
            acc += xv.z * sW[(k4 * 4 + 2) * HD + lane];
            acc += xv.w * sW[(k4 * 4 + 3) * HD + lane];
        }
        h1[(size_t)row * HD + lane] = acc;
        float vs = acc * sAs[lane];
        float vd = acc * sAd[lane];
        #pragma unroll
        for (int o = 4; o > 0; o >>= 1) {
            vs += __shfl_down(vs, o, 8);
            vd += __shfl_down(vd, o, 8);
        }
        if ((lane & 7) == 0) {
            int h = lane >> 3;
            a_src[row * NH + h] = vs;
            a_dst[row * NH + h] = vd;
        }
    }
}

// ---------------- CSR build ---------------------------------------------------
__global__ __launch_bounds__(256) void k_hist(
    const int* __restrict__ dst, int* __restrict__ deg, long E)
{
    long i = (long)blockIdx.x * 256 + threadIdx.x;
    if (i < E) atomicAdd(&deg[dst[i]], 1);
}

__global__ __launch_bounds__(256) void k_bsum(
    const int* __restrict__ deg, int* __restrict__ bsum, int N)
{
    __shared__ int s[256];
    int t = threadIdx.x;
    int i = blockIdx.x * 256 + t;
    s[t] = (i < N) ? deg[i] : 0;
    __syncthreads();
    #pragma unroll
    for (int o = 128; o > 0; o >>= 1) {
        if (t < o) s[t] += s[t + o];
        __syncthreads();
    }
    if (t == 0) bsum[blockIdx.x] = s[0];
}

__global__ __launch_bounds__(512) void k_scan_bsum(
    const int* __restrict__ bsum, int* __restrict__ bexc, int NB)
{
    __shared__ int s[512];
    int t = threadIdx.x;
    s[t] = (t < NB) ? bsum[t] : 0;
    __syncthreads();
    for (int o = 1; o < 512; o <<= 1) {
        int v = (t >= o) ? s[t - o] : 0;
        __syncthreads();
        s[t] += v;
        __syncthreads();
    }
    if (t < NB) bexc[t] = (t == 0) ? 0 : s[t - 1];
}

__global__ __launch_bounds__(256) void k_rowptr(
    const int* __restrict__ deg, const int* __restrict__ bexc,
    int* __restrict__ rowptr, int N, int Etot)
{
    __shared__ int s[256];
    int t = threadIdx.x;
    int i = blockIdx.x * 256 + t;
    int v = (i < N) ? deg[i] : 0;
    s[t] = v;
    __syncthreads();
    for (int o = 1; o < 256; o <<= 1) {
        int u = (t >= o) ? s[t - o] : 0;
        __syncthreads();
        s[t] += u;
        __syncthreads();
    }
    if (i < N) rowptr[i] = bexc[blockIdx.x] + s[t] - v;  // exclusive
    if (i == 0) rowptr[N] = Etot;
}

__global__ __launch_bounds__(256) void k_fill(
    const int* __restrict__ src, const int* __restrict__ dst,
    const int* __restrict__ rowptr, int* __restrict__ cursor,
    int* __restrict__ csr, long E)
{
    long i = (long)blockIdx.x * 256 + threadIdx.x;
    if (i >= E) return;
    int d = dst[i];
    int p = rowptr[d] + atomicAdd(&cursor[d], 1);
    csr[p] = src[i];
}

// ---------------- K-gather1: wave per dst, lane = h*8+j ----------------------
__global__ __launch_bounds__(256) void k_gather1(
    const int* __restrict__ rowptr, const int* __restrict__ csr,
    const float* __restrict__ h1, const float* __restrict__ a_src,
    const float* __restrict__ a_dst, float* __restrict__ agg, int N)
{
    int wave = threadIdx.x >> 6, lane = threadIdx.x & 63;
    int d = blockIdx.x * 4 + wave;
    if (d >= N) return;
    int h = lane >> 3;
    float adst = a_dst[d * NH + h];
    // self-loop (not stored in CSR)
    float w = expf(lrelu(a_src[d * NH + h] + adst));
    float acc = w * h1[(size_t)d * HD + lane];
    float wsum = w;
    int jb = rowptr[d], je = rowptr[d + 1];
    int j = jb;
    for (; j + 1 < je; j += 2) {   // 2-way unroll for memory-level parallelism
        int s0 = csr[j], s1 = csr[j + 1];
        float e0 = a_src[s0 * NH + h] + adst;
        float e1 = a_src[s1 * NH + h] + adst;
        float g0 = h1[(size_t)s0 * HD + lane];
        float g1 = h1[(size_t)s1 * HD + lane];
        float w0 = expf(lrelu(e0));
        float w1 = expf(lrelu(e1));
        acc += w0 * g0 + w1 * g1;
        wsum += w0 + w1;
    }
    if (j < je) {
        int s0 = csr[j];
        float w0 = expf(lrelu(a_src[s0 * NH + h] + adst));
        acc += w0 * h1[(size_t)s0 * HD + lane];
        wsum += w0;
    }
    agg[(size_t)d * HD + lane] = acc / (wsum + 1e-16f);
}

// ------- K4: emb = agg1+b1 (OUT0); x2 = elu(emb); h2p = x2@W2; a_*2 ----------
__global__ __launch_bounds__(256) void k_node2(
    const float* __restrict__ agg1, const float* __restrict__ b1,
    const float* __restrict__ W2, const float* __restrict__ att_s2,
    const float* __restrict__ att_d2, float* __restrict__ emb_out,
    float* __restrict__ h2p, float* __restrict__ a_src2, float* __restrict__ a_dst2,
    int N)
{
    __shared__ float sW[HD * NC];
    __shared__ float sb[HD];
    __shared__ float sas[NC], sad[NC];
    int t = threadIdx.x;
    for (int i = t; i < HD * NC; i += 256) sW[i] = W2[i];
    if (t < HD) sb[t] = b1[t];
    if (t < NC) { sas[t] = att_s2[t]; sad[t] = att_d2[t]; }
    __syncthreads();
    int n = blockIdx.x * 256 + t;
    if (n >= N) return;
    const float* ag = agg1 + (size_t)n * HD;
    float* eo = emb_out + (size_t)n * HD;
    float acc[NC];
    #pragma unroll
    for (int c = 0; c < NC; ++c) acc[c] = 0.f;
    #pragma unroll 8
    for (int k = 0; k < HD; ++k) {
        float v = ag[k] + sb[k];
        eo[k] = v;
        float xv = v > 0.f ? v : expm1f(v);   // jax.nn.elu
        #pragma unroll
        for (int c = 0; c < NC; ++c) acc[c] += xv * sW[k * NC + c];
    }
    float as = 0.f, ad = 0.f;
    float* hp = h2p + (size_t)n * 8;
    #pragma unroll
    for (int c = 0; c < NC; ++c) {
        hp[c] = acc[c];
        as += acc[c] * sas[c];
        ad += acc[c] * sad[c];
    }
    hp[7] = 0.f;
    a_src2[n] = as;
    a_dst2[n] = ad;
}

// ------- K-gather2: thread per dst; fused bias + log_softmax → OUT1 ----------
__global__ __launch_bounds__(256) void k_gather2(
    const int* __restrict__ rowptr, const int* __restrict__ csr,
    const float* __restrict__ h2p, const float* __restrict__ a_src2,
    const float* __restrict__ a_dst2, const float* __restrict__ b2,
    float* __restrict__ out, int N)
{
    int n = blockIdx.x * 256 + threadIdx.x;
    if (n >= N) return;
    float ad = a_dst2[n];
    float w = expf(lrelu(a_src2[n] + ad));     // self-loop
    const float4* hp = (const float4*)(h2p + (size_t)n * 8);
    float4 v0 = hp[0], v1 = hp[1];
    float a0 = w * v0.x, a1 = w * v0.y, a2 = w * v0.z, a3 = w * v0.w;
    float a4 = w * v1.x, a5 = w * v1.y, a6 = w * v1.z;
    float wsum = w;
    int jb = rowptr[n], je = rowptr[n + 1];
    for (int j = jb; j < je; ++j) {
        int s = csr[j];
        float ww = expf(lrelu(a_src2[s] + ad));
        const float4* sp = (const float4*)(h2p + (size_t)s * 8);
        float4 u0 = sp[0], u1 = sp[1];
        a0 += ww * u0.x; a1 += ww * u0.y; a2 += ww * u0.z; a3 += ww * u0.w;
        a4 += ww * u1.x; a5 += ww * u1.y; a6 += ww * u1.z;
        wsum += ww;
    }
    float inv = 1.f / (wsum + 1e-16f);
    float l[NC];
    l[0] = a0 * inv + b2[0]; l[1] = a1 * inv + b2[1]; l[2] = a2 * inv + b2[2];
    l[3] = a3 * inv + b2[3]; l[4] = a4 * inv + b2[4]; l[5] = a5 * inv + b2[5];
    l[6] = a6 * inv + b2[6];
    float m = l[0];
    #pragma unroll
    for (int c = 1; c < NC; ++c) m = fmaxf(m, l[c]);
    float sum = 0.f;
    #pragma unroll
    for (int c = 0; c < NC; ++c) sum += expf(l[c] - m);
    float lse = logf(sum);
    float* op = out + (size_t)n * NC;
    #pragma unroll
    for (int c = 0; c < NC; ++c) op[c] = l[c] - m - lse;
}

extern "C" void kernel_launch(void* const* d_in, const int* in_sizes, int n_in,
                              void* d_out, int out_size, void* d_ws, size_t ws_size,
                              hipStream_t stream)
{
    const float* x       = (const float*)d_in[0];
    const int*   ei      = (const int*)d_in[1];
    const float* W1      = (const float*)d_in[2];
    const float* att_s1  = (const float*)d_in[3];
    const float* att_d1  = (const float*)d_in[4];
    const float* b1      = (const float*)d_in[5];
    const float* W2      = (const float*)d_in[6];
    const float* att_s2  = (const float*)d_in[7];
    const float* att_d2  = (const float*)d_in[8];
    const float* b2      = (const float*)d_in[9];

    const int  N = in_sizes[0] / F_IN;
    const long E = (long)in_sizes[1] / 2;
    const int* src = ei;
    const int* dst = ei + E;

    const int Npad  = (N + 3) & ~3;
    const int Np1p  = (N + 4) & ~3;          // N+1 rounded up to mult of 4
    const long Epad = (E + 3) & ~3;

    // ---- workspace layout (16B-aligned regions) ----
    int* deg    = (int*)d_ws;                 // Npad   (zeroed)
    int* cursor = deg + Npad;                 // Npad   (zeroed)
    int* rowptr = cursor + Npad;              // N+1
    int* bexc   = rowptr + Np1p;              // 512
    int* bsum   = bexc + 512;                 // 512
    int* csr    = bsum + 512;                 // E
    float* h1     = (float*)(csr + Epad);     // N*64
    float* a_src1 = h1 + (size_t)N * HD;      // N*8
    float* a_dst1 = a_src1 + (size_t)N * NH;  // N*8
    float* agg1   = a_dst1 + (size_t)N * NH;  // N*64
    float* h2p    = agg1 + (size_t)N * HD;    // N*8 (padded NC->8)
    float* a_src2 = h2p + (size_t)N * 8;      // Npad
    float* a_dst2 = a_src2 + Npad;            // Npad

    hipMemsetAsync(deg, 0, (size_t)2 * Npad * sizeof(int), stream);

    const int NB = (N + 255) / 256;
    dim3 b256(256);

    // node transform (independent of CSR build — overlapping work for scheduler)
    k_gemm1<<<dim3((N + 63) / 64), b256, 0, stream>>>(x, W1, att_s1, att_d1,
                                                      h1, a_src1, a_dst1, N);
    // CSR build
    k_hist<<<dim3((unsigned)((E + 255) / 256)), b256, 0, stream>>>(dst, deg, E);
    k_bsum<<<dim3(NB), b256, 0, stream>>>(deg, bsum, N);
    k_scan_bsum<<<dim3(1), dim3(512), 0, stream>>>(bsum, bexc, NB);
    k_rowptr<<<dim3(NB), b256, 0, stream>>>(deg, bexc, rowptr, N, (int)E);
    k_fill<<<dim3((unsigned)((E + 255) / 256)), b256, 0, stream>>>(
        src, dst, rowptr, cursor, csr, E);

    // Layer 1 aggregate (no atomics)
    k_gather1<<<dim3((N + 3) / 4), b256, 0, stream>>>(
        rowptr, csr, h1, a_src1, a_dst1, agg1, N);

    // emb output + layer-2 prologue
    float* emb = (float*)d_out;               // N*64
    float* lsm = emb + (size_t)N * HD;        // N*7
    k_node2<<<dim3(NB), b256, 0, stream>>>(
        agg1, b1, W2, att_s2, att_d2, emb, h2p, a_src2, a_dst2, N);

    // Layer 2 aggregate + log_softmax (no atomics)
    k_gather2<<<dim3(NB), b256, 0, stream>>>(
        rowptr, csr, h2p, a_src2, a_dst2, b2, lsm, N);
}

// Round 3
// 835.715 us; speedup vs baseline: 10.5619x; 1.0794x over previous
//
#include <hip/hip_runtime.h>
#include <hip/hip_bf16.h>
#include <math.h>

#define F_IN 128
#define HD   64    // H*D layer1
#define NH   8
#define DH   8
#define NC   7     // classes

__device__ __forceinline__ float lrelu(float e) { return e >= 0.f ? e : 0.2f * e; }
__device__ __forceinline__ float bf2f(ushort u) {
    return __uint_as_float(((unsigned)u) << 16);
}
__device__ __forceinline__ ushort f2bf(float f) {
    // round-to-nearest-even bf16
    unsigned u = __float_as_uint(f);
    unsigned rounded = u + 0x7FFF + ((u >> 16) & 1);
    return (ushort)(rounded >> 16);
}

// ---------------- K1: h1b = bf16(x@W1), a_src1/a_dst1 = (h1*att).sum(-1) -----
__global__ __launch_bounds__(256) void k_gemm1(
    const float* __restrict__ x, const float* __restrict__ W1,
    const float* __restrict__ att_src, const float* __restrict__ att_dst,
    ushort* __restrict__ h1b, float* __restrict__ a_src, float* __restrict__ a_dst,
    int N)
{
    __shared__ float sW[F_IN * HD];      // 32 KB
    __shared__ float sAs[HD], sAd[HD];
    int t = threadIdx.x;
    for (int i = t; i < F_IN * HD; i += 256) sW[i] = W1[i];
    if (t < HD) { sAs[t] = att_src[t]; sAd[t] = att_dst[t]; }
    __syncthreads();

    int lane = t & 63;
    int wave = t >> 6;
    int base = blockIdx.x * 64;

    for (int it = 0; it < 16; ++it) {
        int row = base + it * 4 + wave;
        if (row >= N) continue;
        const float4* xr4 = (const float4*)(x + (size_t)row * F_IN);
        float acc = 0.f;
        #pragma unroll 8
        for (int k4 = 0; k4 < F_IN / 4; ++k4) {
            float4 xv = xr4[k4];
            acc += xv.x * sW[(k4 * 4 + 0) * HD + lane];
            acc += xv.y * sW[(k4 * 4 + 1) * HD + lane];
            acc += xv.z * sW[(k4 * 4 + 2) * HD + lane];
            acc += xv.w * sW[(k4 * 4 + 3) * HD + lane];
        }
        h1b[(size_t)row * HD + lane] = f2bf(acc);
        float vs = acc * sAs[lane];
        float vd = acc * sAd[lane];
        #pragma unroll
        for (int o = 4; o > 0; o >>= 1) {
            vs += __shfl_down(vs, o, 8);
            vd += __shfl_down(vd, o, 8);
        }
        if ((lane & 7) == 0) {
            int h = lane >> 3;
            a_src[row * NH + h] = vs;
            a_dst[row * NH + h] = vd;
        }
    }
}

// ---------------- CSR build ---------------------------------------------------
__global__ __launch_bounds__(256) void k_hist(
    const int* __restrict__ dst, int* __restrict__ deg, long E)
{
    long i = (long)blockIdx.x * 256 + threadIdx.x;
    if (i < E) atomicAdd(&deg[dst[i]], 1);
}

__global__ __launch_bounds__(256) void k_bsum(
    const int* __restrict__ deg, int* __restrict__ bsum, int N)
{
    __shared__ int s[256];
    int t = threadIdx.x;
    int i = blockIdx.x * 256 + t;
    s[t] = (i < N) ? deg[i] : 0;
    __syncthreads();
    #pragma unroll
    for (int o = 128; o > 0; o >>= 1) {
        if (t < o) s[t] += s[t + o];
        __syncthreads();
    }
    if (t == 0) bsum[blockIdx.x] = s[0];
}

__global__ __launch_bounds__(512) void k_scan_bsum(
    const int* __restrict__ bsum, int* __restrict__ bexc, int NB)
{
    __shared__ int s[512];
    int t = threadIdx.x;
    s[t] = (t < NB) ? bsum[t] : 0;
    __syncthreads();
    for (int o = 1; o < 512; o <<= 1) {
        int v = (t >= o) ? s[t - o] : 0;
        __syncthreads();
        s[t] += v;
        __syncthreads();
    }
    if (t < NB) bexc[t] = (t == 0) ? 0 : s[t - 1];
}

__global__ __launch_bounds__(256) void k_rowptr(
    const int* __restrict__ deg, const int* __restrict__ bexc,
    int* __restrict__ rowptr, int N, int Etot)
{
    __shared__ int s[256];
    int t = threadIdx.x;
    int i = blockIdx.x * 256 + t;
    int v = (i < N) ? deg[i] : 0;
    s[t] = v;
    __syncthreads();
    for (int o = 1; o < 256; o <<= 1) {
        int u = (t >= o) ? s[t - o] : 0;
        __syncthreads();
        s[t] += u;
        __syncthreads();
    }
    if (i < N) rowptr[i] = bexc[blockIdx.x] + s[t] - v;  // exclusive
    if (i == 0) rowptr[N] = Etot;
}

__global__ __launch_bounds__(256) void k_fill(
    const int* __restrict__ src, const int* __restrict__ dst,
    const int* __restrict__ rowptr, int* __restrict__ cursor,
    int* __restrict__ csr, long E)
{
    long i = (long)blockIdx.x * 256 + threadIdx.x;
    if (i >= E) return;
    int d = dst[i];
    int p = rowptr[d] + atomicAdd(&cursor[d], 1);
    csr[p] = src[i];
}

// ---------------- K-gather1: wave per dst, lane = h*8+j ----------------------
__global__ __launch_bounds__(256) void k_gather1(
    const int* __restrict__ rowptr, const int* __restrict__ csr,
    const ushort* __restrict__ h1b, const float* __restrict__ a_src,
    const float* __restrict__ a_dst, float* __restrict__ agg, int N)
{
    int wave = threadIdx.x >> 6, lane = threadIdx.x & 63;
    int d = blockIdx.x * 4 + wave;
    if (d >= N) return;
    int h = lane >> 3;
    float adst = a_dst[d * NH + h];
    // self-loop (not stored in CSR)
    float w = __expf(lrelu(a_src[d * NH + h] + adst));
    float acc = w * bf2f(h1b[(size_t)d * HD + lane]);
    float wsum = w;
    int jb = rowptr[d], je = rowptr[d + 1];
    int j = jb;
    for (; j + 3 < je; j += 4) {   // 4-way unroll for memory-level parallelism
        int s0 = csr[j], s1 = csr[j + 1], s2 = csr[j + 2], s3 = csr[j + 3];
        float e0 = a_src[s0 * NH + h] + adst;
        float e1 = a_src[s1 * NH + h] + adst;
        float e2 = a_src[s2 * NH + h] + adst;
        float e3 = a_src[s3 * NH + h] + adst;
        float g0 = bf2f(h1b[(size_t)s0 * HD + lane]);
        float g1 = bf2f(h1b[(size_t)s1 * HD + lane]);
        float g2 = bf2f(h1b[(size_t)s2 * HD + lane]);
        float g3 = bf2f(h1b[(size_t)s3 * HD + lane]);
        float w0 = __expf(lrelu(e0));
        float w1 = __expf(lrelu(e1));
        float w2 = __expf(lrelu(e2));
        float w3 = __expf(lrelu(e3));
        acc += w0 * g0 + w1 * g1 + w2 * g2 + w3 * g3;
        wsum += (w0 + w1) + (w2 + w3);
    }
    for (; j < je; ++j) {
        int s0 = csr[j];
        float w0 = __expf(lrelu(a_src[s0 * NH + h] + adst));
        acc += w0 * bf2f(h1b[(size_t)s0 * HD + lane]);
        wsum += w0;
    }
    agg[(size_t)d * HD + lane] = acc / (wsum + 1e-16f);
}

// ------- K4: emb = agg1+b1 (OUT0); x2 = elu(emb); h2p = x2@W2; a_*2 ----------
__global__ __launch_bounds__(256) void k_node2(
    const float* __restrict__ agg1, const float* __restrict__ b1,
    const float* __restrict__ W2, const float* __restrict__ att_s2,
    const float* __restrict__ att_d2, float* __restrict__ emb_out,
    float* __restrict__ h2p, float* __restrict__ a_src2, float* __restrict__ a_dst2,
    int N)
{
    __shared__ float sW[HD * NC];
    __shared__ float sb[HD];
    __shared__ float sas[NC], sad[NC];
    int t = threadIdx.x;
    for (int i = t; i < HD * NC; i += 256) sW[i] = W2[i];
    if (t < HD) sb[t] = b1[t];
    if (t < NC) { sas[t] = att_s2[t]; sad[t] = att_d2[t]; }
    __syncthreads();
    int n = blockIdx.x * 256 + t;
    if (n >= N) return;
    const float* ag = agg1 + (size_t)n * HD;
    float* eo = emb_out + (size_t)n * HD;
    float acc[NC];
    #pragma unroll
    for (int c = 0; c < NC; ++c) acc[c] = 0.f;
    #pragma unroll 8
    for (int k = 0; k < HD; ++k) {
        float v = ag[k] + sb[k];
        eo[k] = v;
        float xv = v > 0.f ? v : expm1f(v);   // jax.nn.elu
        #pragma unroll
        for (int c = 0; c < NC; ++c) acc[c] += xv * sW[k * NC + c];
    }
    float as = 0.f, ad = 0.f;
    float* hp = h2p + (size_t)n * 8;
    #pragma unroll
    for (int c = 0; c < NC; ++c) {
        hp[c] = acc[c];
        as += acc[c] * sas[c];
        ad += acc[c] * sad[c];
    }
    hp[7] = 0.f;
    a_src2[n] = as;
    a_dst2[n] = ad;
}

// ------- K-gather2: 8 lanes per dst (lane=channel); fused log_softmax → OUT1 -
__global__ __launch_bounds__(256) void k_gather2(
    const int* __restrict__ rowptr, const int* __restrict__ csr,
    const float* __restrict__ h2p, const float* __restrict__ a_src2,
    const float* __restrict__ a_dst2, const float* __restrict__ b2,
    float* __restrict__ out, int N)
{
    int t = threadIdx.x;
    int lane = t & 63;
    int c = lane & 7;            // channel (7 = pad)
    int n = (blockIdx.x * 256 + t) >> 3;  // 32 nodes per block
    if (n >= N) return;
    float ad = a_dst2[n];
    float w = __expf(lrelu(a_src2[n] + ad));   // self-loop
    float acc = w * h2p[(size_t)n * 8 + c];
    float wsum = w;
    int jb = rowptr[n], je = rowptr[n + 1];
    int j = jb;
    for (; j + 1 < je; j += 2) {
        int s0 = csr[j], s1 = csr[j + 1];
        float w0 = __expf(lrelu(a_src2[s0] + ad));
        float w1 = __expf(lrelu(a_src2[s1] + ad));
        float g0 = h2p[(size_t)s0 * 8 + c];
        float g1 = h2p[(size_t)s1 * 8 + c];
        acc += w0 * g0 + w1 * g1;
        wsum += w0 + w1;
    }
    if (j < je) {
        int s0 = csr[j];
        float w0 = __expf(lrelu(a_src2[s0] + ad));
        acc += w0 * h2p[(size_t)s0 * 8 + c];
        wsum += w0;
    }
    float l = (c < NC) ? (acc / (wsum + 1e-16f) + b2[c]) : -1e30f;
    // log_softmax across the 8-lane subgroup (7 valid channels)
    float m = l;
    #pragma unroll
    for (int o = 4; o > 0; o >>= 1) m = fmaxf(m, __shfl_xor(m, o, 8));
    float ex = (c < NC) ? __expf(l - m) : 0.f;
    float s8 = ex;
    #pragma unroll
    for (int o = 4; o > 0; o >>= 1) s8 += __shfl_xor(s8, o, 8);
    float lse = logf(s8);
    if (c < NC) out[(size_t)n * NC + c] = l - m - lse;
}

extern "C" void kernel_launch(void* const* d_in, const int* in_sizes, int n_in,
                              void* d_out, int out_size, void* d_ws, size_t ws_size,
                              hipStream_t stream)
{
    const float* x       = (const float*)d_in[0];
    const int*   ei      = (const int*)d_in[1];
    const float* W1      = (const float*)d_in[2];
    const float* att_s1  = (const float*)d_in[3];
    const float* att_d1  = (const float*)d_in[4];
    const float* b1      = (const float*)d_in[5];
    const float* W2      = (const float*)d_in[6];
    const float* att_s2  = (const float*)d_in[7];
    const float* att_d2  = (const float*)d_in[8];
    const float* b2      = (const float*)d_in[9];

    const int  N = in_sizes[0] / F_IN;
    const long E = (long)in_sizes[1] / 2;
    const int* src = ei;
    const int* dst = ei + E;

    const int Npad  = (N + 3) & ~3;
    const int Np1p  = (N + 4) & ~3;          // N+1 rounded up to mult of 4
    const long Epad = (E + 3) & ~3;

    // ---- workspace layout (16B-aligned regions) ----
    int* deg    = (int*)d_ws;                 // Npad   (zeroed)
    int* cursor = deg + Npad;                 // Npad   (zeroed)
    int* rowptr = cursor + Npad;              // N+1
    int* bexc   = rowptr + Np1p;              // 512
    int* bsum   = bexc + 512;                 // 512
    int* csr    = bsum + 512;                 // E
    ushort* h1b   = (ushort*)(csr + Epad);    // N*64 bf16
    float* a_src1 = (float*)(h1b + (size_t)Npad * HD); // N*8
    float* a_dst1 = a_src1 + (size_t)N * NH;  // N*8
    float* agg1   = a_dst1 + (size_t)N * NH;  // N*64
    float* h2p    = agg1 + (size_t)N * HD;    // N*8 (padded NC->8)
    float* a_src2 = h2p + (size_t)N * 8;      // Npad
    float* a_dst2 = a_src2 + Npad;            // Npad

    hipMemsetAsync(deg, 0, (size_t)2 * Npad * sizeof(int), stream);

    const int NB = (N + 255) / 256;
    dim3 b256(256);

    // node transform (independent of CSR build)
    k_gemm1<<<dim3((N + 63) / 64), b256, 0, stream>>>(x, W1, att_s1, att_d1,
                                                      h1b, a_src1, a_dst1, N);
    // CSR build
    k_hist<<<dim3((unsigned)((E + 255) / 256)), b256, 0, stream>>>(dst, deg, E);
    k_bsum<<<dim3(NB), b256, 0, stream>>>(deg, bsum, N);
    k_scan_bsum<<<dim3(1), dim3(512), 0, stream>>>(bsum, bexc, NB);
    k_rowptr<<<dim3(NB), b256, 0, stream>>>(deg, bexc, rowptr, N, (int)E);
    k_fill<<<dim3((unsigned)((E + 255) / 256)), b256, 0, stream>>>(
        src, dst, rowptr, cursor, csr, E);

    // Layer 1 aggregate (no atomics)
    k_gather1<<<dim3((N + 3) / 4), b256, 0, stream>>>(
        rowptr, csr, h1b, a_src1, a_dst1, agg1, N);

    // emb output + layer-2 prologue
    float* emb = (float*)d_out;               // N*64
    float* lsm = emb + (size_t)N * HD;        // N*7
    k_node2<<<dim3(NB), b256, 0, stream>>>(
        agg1, b1, W2, att_s2, att_d2, emb, h2p, a_src2, a_dst2, N);

    // Layer 2 aggregate + fused log_softmax (no atomics)
    k_gather2<<<dim3((N * 8 + 255) / 256), b256, 0, stream>>>(
        rowptr, csr, h2p, a_src2, a_dst2, b2, lsm, N);
}

// Round 4
// 762.887 us; speedup vs baseline: 11.5701x; 1.0955x over previous
//
#include <hip/hip_runtime.h>
#include <hip/hip_bf16.h>
#include <math.h>

#define F_IN 128
#define HD   64    // H*D layer1
#define NH   8
#define DH   8
#define NC   7     // classes

__device__ __forceinline__ float lrelu(float e) { return e >= 0.f ? e : 0.2f * e; }
__device__ __forceinline__ float bf2f(ushort u) {
    return __uint_as_float(((unsigned)u) << 16);
}
__device__ __forceinline__ ushort f2bf(float f) {
    unsigned u = __float_as_uint(f);
    unsigned rounded = u + 0x7FFF + ((u >> 16) & 1);
    return (ushort)(rounded >> 16);
}

// ---------------- K1: h1b = bf16(x@W1), a_src1/a_dst1 = (h1*att).sum(-1) -----
// 8 rows per wave: each sW ds_read amortized over 8 FMAs (LDS pipe was the
// bottleneck at 1 ds_read_b32 per FMA).
__global__ __launch_bounds__(256) void k_gemm1(
    const float* __restrict__ x, const float* __restrict__ W1,
    const float* __restrict__ att_src, const float* __restrict__ att_dst,
    ushort* __restrict__ h1b, float* __restrict__ a_src, float* __restrict__ a_dst,
    int N)
{
    __shared__ float sW[F_IN * HD];      // 32 KB
    __shared__ float sAs[HD], sAd[HD];
    int t = threadIdx.x;
    for (int i = t; i < F_IN * HD; i += 256) sW[i] = W1[i];
    if (t < HD) { sAs[t] = att_src[t]; sAd[t] = att_dst[t]; }
    __syncthreads();

    int lane = t & 63;
    int wave = t >> 6;
    int base = blockIdx.x * 64 + wave * 16;

    for (int it = 0; it < 2; ++it) {
        int r0 = base + it * 8;
        if (r0 >= N) break;
        int nr = N - r0; if (nr > 8) nr = 8;
        float acc[8];
        #pragma unroll
        for (int r = 0; r < 8; ++r) acc[r] = 0.f;

        if (nr == 8) {
            for (int k4 = 0; k4 < F_IN / 4; ++k4) {
                float4 xv[8];
                #pragma unroll
                for (int r = 0; r < 8; ++r)
                    xv[r] = *(const float4*)(x + (size_t)(r0 + r) * F_IN + k4 * 4);
                #pragma unroll
                for (int kk = 0; kk < 4; ++kk) {
                    float sw = sW[(k4 * 4 + kk) * HD + lane];
                    acc[0] += ((const float*)&xv[0])[kk] * sw;
                    acc[1] += ((const float*)&xv[1])[kk] * sw;
                    acc[2] += ((const float*)&xv[2])[kk] * sw;
                    acc[3] += ((const float*)&xv[3])[kk] * sw;
                    acc[4] += ((const float*)&xv[4])[kk] * sw;
                    acc[5] += ((const float*)&xv[5])[kk] * sw;
                    acc[6] += ((const float*)&xv[6])[kk] * sw;
                    acc[7] += ((const float*)&xv[7])[kk] * sw;
                }
            }
        } else {
            #pragma unroll
            for (int r = 0; r < 8; ++r) {
                if (r < nr) {
                    const float4* xr4 = (const float4*)(x + (size_t)(r0 + r) * F_IN);
                    float a = 0.f;
                    for (int k4 = 0; k4 < F_IN / 4; ++k4) {
                        float4 q = xr4[k4];
                        a += q.x * sW[(k4 * 4 + 0) * HD + lane];
                        a += q.y * sW[(k4 * 4 + 1) * HD + lane];
                        a += q.z * sW[(k4 * 4 + 2) * HD + lane];
                        a += q.w * sW[(k4 * 4 + 3) * HD + lane];
                    }
                    acc[r] = a;
                }
            }
        }
        #pragma unroll
        for (int r = 0; r < 8; ++r) {
            if (r < nr) {
                int row = r0 + r;
                float a = acc[r];
                h1b[(size_t)row * HD + lane] = f2bf(a);
                float vs = a * sAs[lane];
                float vd = a * sAd[lane];
                #pragma unroll
                for (int o = 4; o > 0; o >>= 1) {
                    vs += __shfl_down(vs, o, 8);
                    vd += __shfl_down(vd, o, 8);
                }
                if ((lane & 7) == 0) {
                    int h = lane >> 3;
                    a_src[row * NH + h] = vs;
                    a_dst[row * NH + h] = vd;
                }
            }
        }
    }
}

// ---------------- CSR build ---------------------------------------------------
// hist also records each edge's rank within its dst row (atomicAdd return),
// so k_fill needs no cursor atomics.
__global__ __launch_bounds__(256) void k_hist(
    const int* __restrict__ dst, int* __restrict__ deg, int* __restrict__ rank,
    long E)
{
    long i = (long)blockIdx.x * 256 + threadIdx.x;
    if (i < E) rank[i] = atomicAdd(&deg[dst[i]], 1);
}

__global__ __launch_bounds__(256) void k_bsum(
    const int* __restrict__ deg, int* __restrict__ bsum, int N)
{
    __shared__ int s[256];
    int t = threadIdx.x;
    int i = blockIdx.x * 256 + t;
    s[t] = (i < N) ? deg[i] : 0;
    __syncthreads();
    #pragma unroll
    for (int o = 128; o > 0; o >>= 1) {
        if (t < o) s[t] += s[t + o];
        __syncthreads();
    }
    if (t == 0) bsum[blockIdx.x] = s[0];
}

__global__ __launch_bounds__(512) void k_scan_bsum(
    const int* __restrict__ bsum, int* __restrict__ bexc, int NB)
{
    __shared__ int s[512];
    int t = threadIdx.x;
    s[t] = (t < NB) ? bsum[t] : 0;
    __syncthreads();
    for (int o = 1; o < 512; o <<= 1) {
        int v = (t >= o) ? s[t - o] : 0;
        __syncthreads();
        s[t] += v;
        __syncthreads();
    }
    if (t < NB) bexc[t] = (t == 0) ? 0 : s[t - 1];
}

__global__ __launch_bounds__(256) void k_rowptr(
    const int* __restrict__ deg, const int* __restrict__ bexc,
    int* __restrict__ rowptr, int N, int Etot)
{
    __shared__ int s[256];
    int t = threadIdx.x;
    int i = blockIdx.x * 256 + t;
    int v = (i < N) ? deg[i] : 0;
    s[t] = v;
    __syncthreads();
    for (int o = 1; o < 256; o <<= 1) {
        int u = (t >= o) ? s[t - o] : 0;
        __syncthreads();
        s[t] += u;
        __syncthreads();
    }
    if (i < N) rowptr[i] = bexc[blockIdx.x] + s[t] - v;  // exclusive
    if (i == 0) rowptr[N] = Etot;
}

__global__ __launch_bounds__(256) void k_fill(
    const int* __restrict__ src, const int* __restrict__ dst,
    const int* __restrict__ rank, const int* __restrict__ rowptr,
    int* __restrict__ csr, long E)
{
    long i = (long)blockIdx.x * 256 + threadIdx.x;
    if (i >= E) return;
    csr[rowptr[dst[i]] + rank[i]] = src[i];
}

// ---------------- K-gather1: wave per dst, lane = h*8+j ----------------------
__global__ __launch_bounds__(256) void k_gather1(
    const int* __restrict__ rowptr, const int* __restrict__ csr,
    const ushort* __restrict__ h1b, const float* __restrict__ a_src,
    const float* __restrict__ a_dst, float* __restrict__ agg, int N)
{
    int wave = threadIdx.x >> 6, lane = threadIdx.x & 63;
    int d = blockIdx.x * 4 + wave;
    if (d >= N) return;
    int h = lane >> 3;
    float adst = a_dst[d * NH + h];
    float w = __expf(lrelu(a_src[d * NH + h] + adst));  // self-loop
    float acc = w * bf2f(h1b[(size_t)d * HD + lane]);
    float wsum = w;
    int jb = rowptr[d], je = rowptr[d + 1];
    int j = jb;
    for (; j + 3 < je; j += 4) {
        int s0 = csr[j], s1 = csr[j + 1], s2 = csr[j + 2], s3 = csr[j + 3];
        float e0 = a_src[s0 * NH + h] + adst;
        float e1 = a_src[s1 * NH + h] + adst;
        float e2 = a_src[s2 * NH + h] + adst;
        float e3 = a_src[s3 * NH + h] + adst;
        float g0 = bf2f(h1b[(size_t)s0 * HD + lane]);
        float g1 = bf2f(h1b[(size_t)s1 * HD + lane]);
        float g2 = bf2f(h1b[(size_t)s2 * HD + lane]);
        float g3 = bf2f(h1b[(size_t)s3 * HD + lane]);
        float w0 = __expf(lrelu(e0));
        float w1 = __expf(lrelu(e1));
        float w2 = __expf(lrelu(e2));
        float w3 = __expf(lrelu(e3));
        acc += w0 * g0 + w1 * g1 + w2 * g2 + w3 * g3;
        wsum += (w0 + w1) + (w2 + w3);
    }
    for (; j < je; ++j) {
        int s0 = csr[j];
        float w0 = __expf(lrelu(a_src[s0 * NH + h] + adst));
        acc += w0 * bf2f(h1b[(size_t)s0 * HD + lane]);
        wsum += w0;
    }
    agg[(size_t)d * HD + lane] = acc / (wsum + 1e-16f);
}

// ------- K4: emb = agg1+b1 (OUT0); x2 = elu(emb); h2p = x2@W2; a_*2 ----------
__global__ __launch_bounds__(256) void k_node2(
    const float* __restrict__ agg1, const float* __restrict__ b1,
    const float* __restrict__ W2, const float* __restrict__ att_s2,
    const float* __restrict__ att_d2, float* __restrict__ emb_out,
    float* __restrict__ h2p, float* __restrict__ a_src2, float* __restrict__ a_dst2,
    int N)
{
    __shared__ float sW[HD * NC];
    __shared__ float sb[HD];
    __shared__ float sas[NC], sad[NC];
    int t = threadIdx.x;
    for (int i = t; i < HD * NC; i += 256) sW[i] = W2[i];
    if (t < HD) sb[t] = b1[t];
    if (t < NC) { sas[t] = att_s2[t]; sad[t] = att_d2[t]; }
    __syncthreads();
    int n = blockIdx.x * 256 + t;
    if (n >= N) return;
    const float* ag = agg1 + (size_t)n * HD;
    float* eo = emb_out + (size_t)n * HD;
    float acc[NC];
    #pragma unroll
    for (int c = 0; c < NC; ++c) acc[c] = 0.f;
    #pragma unroll 8
    for (int k = 0; k < HD; ++k) {
        float v = ag[k] + sb[k];
        eo[k] = v;
        float xv = v > 0.f ? v : expm1f(v);   // jax.nn.elu
        #pragma unroll
        for (int c = 0; c < NC; ++c) acc[c] += xv * sW[k * NC + c];
    }
    float as = 0.f, ad = 0.f;
    float* hp = h2p + (size_t)n * 8;
    #pragma unroll
    for (int c = 0; c < NC; ++c) {
        hp[c] = acc[c];
        as += acc[c] * sas[c];
        ad += acc[c] * sad[c];
    }
    hp[7] = 0.f;
    a_src2[n] = as;
    a_dst2[n] = ad;
}

// ------- K-gather2: WAVE per dst; lane = edge-slot*8 + channel ---------------
// No degree divergence within the wave; cross-slot shfl_xor reduction; fused
// bias + log_softmax epilogue.
__global__ __launch_bounds__(256) void k_gather2(
    const int* __restrict__ rowptr, const int* __restrict__ csr,
    const float* __restrict__ h2p, const float* __restrict__ a_src2,
    const float* __restrict__ a_dst2, const float* __restrict__ b2,
    float* __restrict__ out, int N)
{
    int t = threadIdx.x;
    int wave = t >> 6, lane = t & 63;
    int g = lane >> 3;           // edge slot 0..7
    int c = lane & 7;            // channel (7 = pad)
    int n = blockIdx.x * 4 + wave;
    if (n >= N) return;
    float ad = a_dst2[n];
    float w = __expf(lrelu(a_src2[n] + ad));   // self-loop
    float acc  = (g == 0) ? w * h2p[(size_t)n * 8 + c] : 0.f;
    float wsum = (g == 0) ? w : 0.f;
    int jb = rowptr[n], je = rowptr[n + 1];
    for (int j = jb; j < je; j += 8) {
        int idx = j + g;
        bool v = idx < je;
        int s = v ? csr[idx] : n;
        float ww = v ? __expf(lrelu(a_src2[s] + ad)) : 0.f;
        acc += ww * h2p[(size_t)s * 8 + c];
        wsum += ww;
    }
    #pragma unroll
    for (int o = 32; o >= 8; o >>= 1) {
        acc  += __shfl_xor(acc, o, 64);
        wsum += __shfl_xor(wsum, o, 64);
    }
    float l = (c < NC) ? (acc / (wsum + 1e-16f) + b2[c]) : -1e30f;
    float m = l;
    #pragma unroll
    for (int o = 4; o > 0; o >>= 1) m = fmaxf(m, __shfl_xor(m, o, 8));
    float ex = (c < NC) ? __expf(l - m) : 0.f;
    float s8 = ex;
    #pragma unroll
    for (int o = 4; o > 0; o >>= 1) s8 += __shfl_xor(s8, o, 8);
    if (g == 0 && c < NC) out[(size_t)n * NC + c] = l - m - logf(s8);
}

extern "C" void kernel_launch(void* const* d_in, const int* in_sizes, int n_in,
                              void* d_out, int out_size, void* d_ws, size_t ws_size,
                              hipStream_t stream)
{
    const float* x       = (const float*)d_in[0];
    const int*   ei      = (const int*)d_in[1];
    const float* W1      = (const float*)d_in[2];
    const float* att_s1  = (const float*)d_in[3];
    const float* att_d1  = (const float*)d_in[4];
    const float* b1      = (const float*)d_in[5];
    const float* W2      = (const float*)d_in[6];
    const float* att_s2  = (const float*)d_in[7];
    const float* att_d2  = (const float*)d_in[8];
    const float* b2      = (const float*)d_in[9];

    const int  N = in_sizes[0] / F_IN;
    const long E = (long)in_sizes[1] / 2;
    const int* src = ei;
    const int* dst = ei + E;

    const int Npad  = (N + 3) & ~3;
    const int Np1p  = (N + 4) & ~3;
    const long Epad = (E + 3) & ~3;

    // ---- workspace layout ----
    int* deg    = (int*)d_ws;                 // Npad   (zeroed)
    int* rowptr = deg + Npad;                 // N+1
    int* bexc   = rowptr + Np1p;              // 512
    int* bsum   = bexc + 512;                 // 512
    int* csr    = bsum + 512;                 // E
    ushort* h1b   = (ushort*)(csr + Epad);    // Npad*64 bf16
    float* a_src1 = (float*)(h1b + (size_t)Npad * HD); // N*8
    float* a_dst1 = a_src1 + (size_t)N * NH;  // N*8
    float* agg1   = a_dst1 + (size_t)N * NH;  // N*64
    float* h2p    = agg1 + (size_t)N * HD;    // N*8 (padded NC->8)
    float* a_src2 = h2p + (size_t)N * 8;      // Npad
    float* a_dst2 = a_src2 + Npad;            // Npad
    float* wsend  = a_dst2 + Npad;
    // rank[E] aliases agg1's space (dead before k_gather1 writes agg1)
    int* rank = (E <= (long)N * HD) ? (int*)agg1 : (int*)wsend;

    hipMemsetAsync(deg, 0, (size_t)Npad * sizeof(int), stream);

    const int NB = (N + 255) / 256;
    dim3 b256(256);

    k_gemm1<<<dim3((N + 63) / 64), b256, 0, stream>>>(x, W1, att_s1, att_d1,
                                                      h1b, a_src1, a_dst1, N);
    // CSR build
    k_hist<<<dim3((unsigned)((E + 255) / 256)), b256, 0, stream>>>(dst, deg, rank, E);
    k_bsum<<<dim3(NB), b256, 0, stream>>>(deg, bsum, N);
    k_scan_bsum<<<dim3(1), dim3(512), 0, stream>>>(bsum, bexc, NB);
    k_rowptr<<<dim3(NB), b256, 0, stream>>>(deg, bexc, rowptr, N, (int)E);
    k_fill<<<dim3((unsigned)((E + 255) / 256)), b256, 0, stream>>>(
        src, dst, rank, rowptr, csr, E);

    // Layer 1 aggregate
    k_gather1<<<dim3((N + 3) / 4), b256, 0, stream>>>(
        rowptr, csr, h1b, a_src1, a_dst1, agg1, N);

    // emb output + layer-2 prologue
    float* emb = (float*)d_out;               // N*64
    float* lsm = emb + (size_t)N * HD;        // N*7
    k_node2<<<dim3(NB), b256, 0, stream>>>(
        agg1, b1, W2, att_s2, att_d2, emb, h2p, a_src2, a_dst2, N);

    // Layer 2 aggregate + fused log_softmax
    k_gather2<<<dim3((N + 3) / 4), b256, 0, stream>>>(
        rowptr, csr, h2p, a_src2, a_dst2, b2, lsm, N);
}

// Round 5
// 756.468 us; speedup vs baseline: 11.6683x; 1.0085x over previous
//
#include <hip/hip_runtime.h>
#include <hip/hip_bf16.h>
#include <math.h>

#define F_IN 128
#define HD   64    // H*D layer1
#define NH   8
#define DH   8
#define NC   7     // classes

__device__ __forceinline__ float lrelu(float e) { return fmaxf(e, 0.2f * e); }
__device__ __forceinline__ float bf2f(ushort u) {
    return __uint_as_float(((unsigned)u) << 16);
}
__device__ __forceinline__ ushort f2bf(float f) {
    unsigned u = __float_as_uint(f);
    unsigned rounded = u + 0x7FFF + ((u >> 16) & 1);
    return (ushort)(rounded >> 16);
}

// ---------------- K1: h1b = bf16(x@W1), a_src1/a_dst1 = (h1*att).sum(-1) -----
__global__ __launch_bounds__(256) void k_gemm1(
    const float* __restrict__ x, const float* __restrict__ W1,
    const float* __restrict__ att_src, const float* __restrict__ att_dst,
    ushort* __restrict__ h1b, float* __restrict__ a_src, float* __restrict__ a_dst,
    int N)
{
    __shared__ float sW[F_IN * HD];      // 32 KB
    __shared__ float sAs[HD], sAd[HD];
    int t = threadIdx.x;
    for (int i = t; i < F_IN * HD; i += 256) sW[i] = W1[i];
    if (t < HD) { sAs[t] = att_src[t]; sAd[t] = att_dst[t]; }
    __syncthreads();

    int lane = t & 63;
    int wave = t >> 6;
    int base = blockIdx.x * 64 + wave * 16;

    for (int it = 0; it < 2; ++it) {
        int r0 = base + it * 8;
        if (r0 >= N) break;
        int nr = N - r0; if (nr > 8) nr = 8;
        float acc[8];
        #pragma unroll
        for (int r = 0; r < 8; ++r) acc[r] = 0.f;

        if (nr == 8) {
            for (int k4 = 0; k4 < F_IN / 4; ++k4) {
                float4 xv[8];
                #pragma unroll
                for (int r = 0; r < 8; ++r)
                    xv[r] = *(const float4*)(x + (size_t)(r0 + r) * F_IN + k4 * 4);
                #pragma unroll
                for (int kk = 0; kk < 4; ++kk) {
                    float sw = sW[(k4 * 4 + kk) * HD + lane];
                    acc[0] += ((const float*)&xv[0])[kk] * sw;
                    acc[1] += ((const float*)&xv[1])[kk] * sw;
                    acc[2] += ((const float*)&xv[2])[kk] * sw;
                    acc[3] += ((const float*)&xv[3])[kk] * sw;
                    acc[4] += ((const float*)&xv[4])[kk] * sw;
                    acc[5] += ((const float*)&xv[5])[kk] * sw;
                    acc[6] += ((const float*)&xv[6])[kk] * sw;
                    acc[7] += ((const float*)&xv[7])[kk] * sw;
                }
            }
        } else {
            #pragma unroll
            for (int r = 0; r < 8; ++r) {
                if (r < nr) {
                    const float4* xr4 = (const float4*)(x + (size_t)(r0 + r) * F_IN);
                    float a = 0.f;
                    for (int k4 = 0; k4 < F_IN / 4; ++k4) {
                        float4 q = xr4[k4];
                        a += q.x * sW[(k4 * 4 + 0) * HD + lane];
                        a += q.y * sW[(k4 * 4 + 1) * HD + lane];
                        a += q.z * sW[(k4 * 4 + 2) * HD + lane];
                        a += q.w * sW[(k4 * 4 + 3) * HD + lane];
                    }
                    acc[r] = a;
                }
            }
        }
        #pragma unroll
        for (int r = 0; r < 8; ++r) {
            if (r < nr) {
                int row = r0 + r;
                float a = acc[r];
                h1b[(size_t)row * HD + lane] = f2bf(a);
                float vs = a * sAs[lane];
                float vd = a * sAd[lane];
                #pragma unroll
                for (int o = 4; o > 0; o >>= 1) {
                    vs += __shfl_down(vs, o, 8);
                    vd += __shfl_down(vd, o, 8);
                }
                if ((lane & 7) == 0) {
                    int h = lane >> 3;
                    a_src[row * NH + h] = vs;
                    a_dst[row * NH + h] = vd;
                }
            }
        }
    }
}

// ---------------- CSR build ---------------------------------------------------
__global__ __launch_bounds__(256) void k_hist(
    const int* __restrict__ dst, int* __restrict__ deg, int* __restrict__ rank,
    long E)
{
    long i = (long)blockIdx.x * 256 + threadIdx.x;
    if (i < E) rank[i] = atomicAdd(&deg[dst[i]], 1);
}

__global__ __launch_bounds__(256) void k_bsum(
    const int* __restrict__ deg, int* __restrict__ bsum, int N)
{
    __shared__ int s[256];
    int t = threadIdx.x;
    int i = blockIdx.x * 256 + t;
    s[t] = (i < N) ? deg[i] : 0;
    __syncthreads();
    #pragma unroll
    for (int o = 128; o > 0; o >>= 1) {
        if (t < o) s[t] += s[t + o];
        __syncthreads();
    }
    if (t == 0) bsum[blockIdx.x] = s[0];
}

__global__ __launch_bounds__(512) void k_scan_bsum(
    const int* __restrict__ bsum, int* __restrict__ bexc, int NB)
{
    __shared__ int s[512];
    int t = threadIdx.x;
    s[t] = (t < NB) ? bsum[t] : 0;
    __syncthreads();
    for (int o = 1; o < 512; o <<= 1) {
        int v = (t >= o) ? s[t - o] : 0;
        __syncthreads();
        s[t] += v;
        __syncthreads();
    }
    if (t < NB) bexc[t] = (t == 0) ? 0 : s[t - 1];
}

__global__ __launch_bounds__(256) void k_rowptr(
    const int* __restrict__ deg, const int* __restrict__ bexc,
    int* __restrict__ rowptr, int N, int Etot)
{
    __shared__ int s[256];
    int t = threadIdx.x;
    int i = blockIdx.x * 256 + t;
    int v = (i < N) ? deg[i] : 0;
    s[t] = v;
    __syncthreads();
    for (int o = 1; o < 256; o <<= 1) {
        int u = (t >= o) ? s[t - o] : 0;
        __syncthreads();
        s[t] += u;
        __syncthreads();
    }
    if (i < N) rowptr[i] = bexc[blockIdx.x] + s[t] - v;  // exclusive
    if (i == 0) rowptr[N] = Etot;
}

__global__ __launch_bounds__(256) void k_fill(
    const int* __restrict__ src, const int* __restrict__ dst,
    const int* __restrict__ rank, const int* __restrict__ rowptr,
    int* __restrict__ csr, long E)
{
    long i = (long)blockIdx.x * 256 + threadIdx.x;
    if (i >= E) return;
    csr[rowptr[dst[i]] + rank[i]] = src[i];
}

// ---------------- K-gather1 v3: wave per dst, 8-edge chunks ------------------
// Phase 1: lane=(e,h) computes 64 DISTINCT exp-weights per issue (8 edges x 8
// heads) — 8x fewer exp/lrelu/a_src issues than lane=(h,j) layout.
// Phase 2: lane=(half, channel-pair); each half-wave does 4 edges; h1b read as
// uint (2 bf16/lane) — half the gather instructions. w/s via shfl (LDS pipe).
__global__ __launch_bounds__(256) void k_gather1(
    const int* __restrict__ rowptr, const int* __restrict__ csr,
    const ushort* __restrict__ h1b, const float* __restrict__ a_src,
    const float* __restrict__ a_dst, float* __restrict__ agg, int N)
{
    const uint* __restrict__ h1u = (const uint*)h1b;
    int wave = threadIdx.x >> 6, lane = threadIdx.x & 63;
    int d = blockIdx.x * 4 + wave;
    if (d >= N) return;

    int e    = lane >> 3;        // edge slot (phase 1)
    int h    = lane & 7;         // head (phase 1)
    int p    = lane & 31;        // channel pair (phase 2): channels 2p,2p+1
    int half = lane >> 5;        // half-wave (phase 2)
    int hp   = p >> 2;           // head of channel 2p
    int e2b  = half * 4;         // this half's first edge slot

    float adst = a_dst[d * NH + h];

    // self-loop
    float ws = __expf(lrelu(a_src[d * NH + h] + adst));
    float wsum = (e == 0) ? ws : 0.f;
    float w2s = __shfl(ws, hp, 64);          // lane hp holds head hp
    uint u0 = h1u[(size_t)d * 32 + p];
    float wini = (half == 0) ? w2s : 0.f;
    float accx = wini * __uint_as_float(u0 << 16);
    float accy = wini * __uint_as_float(u0 & 0xFFFF0000u);

    int jb = rowptr[d], je = rowptr[d + 1];
    for (int j0 = jb; j0 < je; j0 += 8) {
        // phase 1: weights for 8 edges
        int idx = j0 + e;
        bool v = idx < je;
        int sl = v ? csr[idx] : d;
        float w = __expf(lrelu(a_src[sl * NH + h] + adst));
        w = v ? w : 0.f;
        wsum += w;
        // phase 2: accumulate 4 edges per half-wave
        #pragma unroll
        for (int k = 0; k < 4; ++k) {
            int es = e2b + k;
            int   s2 = __shfl(sl, es * 8, 64);
            float w2 = __shfl(w, es * 8 + hp, 64);
            uint  u  = h1u[(size_t)s2 * 32 + p];
            accx += w2 * __uint_as_float(u << 16);
            accy += w2 * __uint_as_float(u & 0xFFFF0000u);
        }
    }

    // reduce wsum over edge slots (lanes sharing h)
    wsum += __shfl_xor(wsum, 8, 64);
    wsum += __shfl_xor(wsum, 16, 64);
    wsum += __shfl_xor(wsum, 32, 64);
    float winv = 1.f / (__shfl(wsum, hp, 64) + 1e-16f);

    // merge the two halves' edge subsets
    accx += __shfl_xor(accx, 32, 64);
    accy += __shfl_xor(accy, 32, 64);
    if (half == 0) {
        ((float2*)agg)[(size_t)d * 32 + p] = make_float2(accx * winv, accy * winv);
    }
}

// ------- K4: emb = agg1+b1 (OUT0); x2 = elu(emb); h2p = x2@W2; a_*2 ----------
__global__ __launch_bounds__(256) void k_node2(
    const float* __restrict__ agg1, const float* __restrict__ b1,
    const float* __restrict__ W2, const float* __restrict__ att_s2,
    const float* __restrict__ att_d2, float* __restrict__ emb_out,
    float* __restrict__ h2p, float* __restrict__ a_src2, float* __restrict__ a_dst2,
    int N)
{
    __shared__ float sW[HD * NC];
    __shared__ float sb[HD];
    __shared__ float sas[NC], sad[NC];
    int t = threadIdx.x;
    for (int i = t; i < HD * NC; i += 256) sW[i] = W2[i];
    if (t < HD) sb[t] = b1[t];
    if (t < NC) { sas[t] = att_s2[t]; sad[t] = att_d2[t]; }
    __syncthreads();
    int n = blockIdx.x * 256 + t;
    if (n >= N) return;
    const float* ag = agg1 + (size_t)n * HD;
    float* eo = emb_out + (size_t)n * HD;
    float acc[NC];
    #pragma unroll
    for (int c = 0; c < NC; ++c) acc[c] = 0.f;
    #pragma unroll 8
    for (int k = 0; k < HD; ++k) {
        float v = ag[k] + sb[k];
        eo[k] = v;
        float xv = v > 0.f ? v : expm1f(v);   // jax.nn.elu
        #pragma unroll
        for (int c = 0; c < NC; ++c) acc[c] += xv * sW[k * NC + c];
    }
    float as = 0.f, ad = 0.f;
    float* hp = h2p + (size_t)n * 8;
    #pragma unroll
    for (int c = 0; c < NC; ++c) {
        hp[c] = acc[c];
        as += acc[c] * sas[c];
        ad += acc[c] * sad[c];
    }
    hp[7] = 0.f;
    a_src2[n] = as;
    a_dst2[n] = ad;
}

// ------- K-gather2: WAVE per dst; lane = edge-slot*8 + channel ---------------
__global__ __launch_bounds__(256) void k_gather2(
    const int* __restrict__ rowptr, const int* __restrict__ csr,
    const float* __restrict__ h2p, const float* __restrict__ a_src2,
    const float* __restrict__ a_dst2, const float* __restrict__ b2,
    float* __restrict__ out, int N)
{
    int t = threadIdx.x;
    int wave = t >> 6, lane = t & 63;
    int g = lane >> 3;           // edge slot 0..7
    int c = lane & 7;            // channel (7 = pad)
    int n = blockIdx.x * 4 + wave;
    if (n >= N) return;
    float ad = a_dst2[n];
    float w = __expf(lrelu(a_src2[n] + ad));   // self-loop
    float acc  = (g == 0) ? w * h2p[(size_t)n * 8 + c] : 0.f;
    float wsum = (g == 0) ? w : 0.f;
    int jb = rowptr[n], je = rowptr[n + 1];
    for (int j = jb; j < je; j += 8) {
        int idx = j + g;
        bool v = idx < je;
        int s = v ? csr[idx] : n;
        float ww = v ? __expf(lrelu(a_src2[s] + ad)) : 0.f;
        acc += ww * h2p[(size_t)s * 8 + c];
        wsum += ww;
    }
    #pragma unroll
    for (int o = 32; o >= 8; o >>= 1) {
        acc  += __shfl_xor(acc, o, 64);
        wsum += __shfl_xor(wsum, o, 64);
    }
    float l = (c < NC) ? (acc / (wsum + 1e-16f) + b2[c]) : -1e30f;
    float m = l;
    #pragma unroll
    for (int o = 4; o > 0; o >>= 1) m = fmaxf(m, __shfl_xor(m, o, 8));
    float ex = (c < NC) ? __expf(l - m) : 0.f;
    float s8 = ex;
    #pragma unroll
    for (int o = 4; o > 0; o >>= 1) s8 += __shfl_xor(s8, o, 8);
    if (g == 0 && c < NC) out[(size_t)n * NC + c] = l - m - logf(s8);
}

extern "C" void kernel_launch(void* const* d_in, const int* in_sizes, int n_in,
                              void* d_out, int out_size, void* d_ws, size_t ws_size,
                              hipStream_t stream)
{
    const float* x       = (const float*)d_in[0];
    const int*   ei      = (const int*)d_in[1];
    const float* W1      = (const float*)d_in[2];
    const float* att_s1  = (const float*)d_in[3];
    const float* att_d1  = (const float*)d_in[4];
    const float* b1      = (const float*)d_in[5];
    const float* W2      = (const float*)d_in[6];
    const float* att_s2  = (const float*)d_in[7];
    const float* att_d2  = (const float*)d_in[8];
    const float* b2      = (const float*)d_in[9];

    const int  N = in_sizes[0] / F_IN;
    const long E = (long)in_sizes[1] / 2;
    const int* src = ei;
    const int* dst = ei + E;

    const int Npad  = (N + 3) & ~3;
    const int Np1p  = (N + 4) & ~3;
    const long Epad = (E + 3) & ~3;

    // ---- workspace layout ----
    int* deg    = (int*)d_ws;                 // Npad   (zeroed)
    int* rowptr = deg + Npad;                 // N+1
    int* bexc   = rowptr + Np1p;              // 512
    int* bsum   = bexc + 512;                 // 512
    int* csr    = bsum + 512;                 // E
    ushort* h1b   = (ushort*)(csr + Epad);    // Npad*64 bf16
    float* a_src1 = (float*)(h1b + (size_t)Npad * HD); // N*8
    float* a_dst1 = a_src1 + (size_t)N * NH;  // N*8
    float* agg1   = a_dst1 + (size_t)N * NH;  // N*64
    float* h2p    = agg1 + (size_t)N * HD;    // N*8 (padded NC->8)
    float* a_src2 = h2p + (size_t)N * 8;      // Npad
    float* a_dst2 = a_src2 + Npad;            // Npad
    float* wsend  = a_dst2 + Npad;
    // rank[E] aliases agg1's space (dead before k_gather1 writes agg1)
    int* rank = (E <= (long)N * HD) ? (int*)agg1 : (int*)wsend;

    hipMemsetAsync(deg, 0, (size_t)Npad * sizeof(int), stream);

    const int NB = (N + 255) / 256;
    dim3 b256(256);

    k_gemm1<<<dim3((N + 63) / 64), b256, 0, stream>>>(x, W1, att_s1, att_d1,
                                                      h1b, a_src1, a_dst1, N);
    // CSR build
    k_hist<<<dim3((unsigned)((E + 255) / 256)), b256, 0, stream>>>(dst, deg, rank, E);
    k_bsum<<<dim3(NB), b256, 0, stream>>>(deg, bsum, N);
    k_scan_bsum<<<dim3(1), dim3(512), 0, stream>>>(bsum, bexc, NB);
    k_rowptr<<<dim3(NB), b256, 0, stream>>>(deg, bexc, rowptr, N, (int)E);
    k_fill<<<dim3((unsigned)((E + 255) / 256)), b256, 0, stream>>>(
        src, dst, rank, rowptr, csr, E);

    // Layer 1 aggregate
    k_gather1<<<dim3((N + 3) / 4), b256, 0, stream>>>(
        rowptr, csr, h1b, a_src1, a_dst1, agg1, N);

    // emb output + layer-2 prologue
    float* emb = (float*)d_out;               // N*64
    float* lsm = emb + (size_t)N * HD;        // N*7
    k_node2<<<dim3(NB), b256, 0, stream>>>(
        agg1, b1, W2, att_s2, att_d2, emb, h2p, a_src2, a_dst2, N);

    // Layer 2 aggregate + fused log_softmax
    k_gather2<<<dim3((N + 3) / 4), b256, 0, stream>>>(
        rowptr, csr, h2p, a_src2, a_dst2, b2, lsm, N);
}

// Round 6
// 736.246 us; speedup vs baseline: 11.9888x; 1.0275x over previous
//
#include <hip/hip_runtime.h>
#include <hip/hip_bf16.h>
#include <math.h>

#define F_IN 128
#define HD   64    // H*D layer1
#define NH   8
#define DH   8
#define NC   7     // classes

__device__ __forceinline__ float lrelu(float e) { return fmaxf(e, 0.2f * e); }
__device__ __forceinline__ float bf2f(ushort u) {
    return __uint_as_float(((unsigned)u) << 16);
}
__device__ __forceinline__ ushort f2bf(float f) {
    unsigned u = __float_as_uint(f);
    unsigned rounded = u + 0x7FFF + ((u >> 16) & 1);
    return (ushort)(rounded >> 16);
}

// ---------------- K1: h1b = bf16(x@W1), a_src1/a_dst1 = (h1*att).sum(-1) -----
__global__ __launch_bounds__(256) void k_gemm1(
    const float* __restrict__ x, const float* __restrict__ W1,
    const float* __restrict__ att_src, const float* __restrict__ att_dst,
    ushort* __restrict__ h1b, float* __restrict__ a_src, float* __restrict__ a_dst,
    int N)
{
    __shared__ float sW[F_IN * HD];      // 32 KB
    __shared__ float sAs[HD], sAd[HD];
    int t = threadIdx.x;
    for (int i = t; i < F_IN * HD; i += 256) sW[i] = W1[i];
    if (t < HD) { sAs[t] = att_src[t]; sAd[t] = att_dst[t]; }
    __syncthreads();

    int lane = t & 63;
    int wave = t >> 6;
    int base = blockIdx.x * 64 + wave * 16;

    for (int it = 0; it < 2; ++it) {
        int r0 = base + it * 8;
        if (r0 >= N) break;
        int nr = N - r0; if (nr > 8) nr = 8;
        float acc[8];
        #pragma unroll
        for (int r = 0; r < 8; ++r) acc[r] = 0.f;

        if (nr == 8) {
            for (int k4 = 0; k4 < F_IN / 4; ++k4) {
                float4 xv[8];
                #pragma unroll
                for (int r = 0; r < 8; ++r)
                    xv[r] = *(const float4*)(x + (size_t)(r0 + r) * F_IN + k4 * 4);
                #pragma unroll
                for (int kk = 0; kk < 4; ++kk) {
                    float sw = sW[(k4 * 4 + kk) * HD + lane];
                    acc[0] += ((const float*)&xv[0])[kk] * sw;
                    acc[1] += ((const float*)&xv[1])[kk] * sw;
                    acc[2] += ((const float*)&xv[2])[kk] * sw;
                    acc[3] += ((const float*)&xv[3])[kk] * sw;
                    acc[4] += ((const float*)&xv[4])[kk] * sw;
                    acc[5] += ((const float*)&xv[5])[kk] * sw;
                    acc[6] += ((const float*)&xv[6])[kk] * sw;
                    acc[7] += ((const float*)&xv[7])[kk] * sw;
                }
            }
        } else {
            #pragma unroll
            for (int r = 0; r < 8; ++r) {
                if (r < nr) {
                    const float4* xr4 = (const float4*)(x + (size_t)(r0 + r) * F_IN);
                    float a = 0.f;
                    for (int k4 = 0; k4 < F_IN / 4; ++k4) {
                        float4 q = xr4[k4];
                        a += q.x * sW[(k4 * 4 + 0) * HD + lane];
                        a += q.y * sW[(k4 * 4 + 1) * HD + lane];
                        a += q.z * sW[(k4 * 4 + 2) * HD + lane];
                        a += q.w * sW[(k4 * 4 + 3) * HD + lane];
                    }
                    acc[r] = a;
                }
            }
        }
        #pragma unroll
        for (int r = 0; r < 8; ++r) {
            if (r < nr) {
                int row = r0 + r;
                float a = acc[r];
                h1b[(size_t)row * HD + lane] = f2bf(a);
                float vs = a * sAs[lane];
                float vd = a * sAd[lane];
                #pragma unroll
                for (int o = 4; o > 0; o >>= 1) {
                    vs += __shfl_down(vs, o, 8);
                    vd += __shfl_down(vd, o, 8);
                }
                if ((lane & 7) == 0) {
                    int h = lane >> 3;
                    a_src[row * NH + h] = vs;
                    a_dst[row * NH + h] = vd;
                }
            }
        }
    }
}

// ---------------- CSR build ---------------------------------------------------
__global__ __launch_bounds__(256) void k_hist(
    const int* __restrict__ dst, int* __restrict__ deg, int* __restrict__ rank,
    long E)
{
    long i = (long)blockIdx.x * 256 + threadIdx.x;
    if (i < E) rank[i] = atomicAdd(&deg[dst[i]], 1);
}

__global__ __launch_bounds__(256) void k_bsum(
    const int* __restrict__ deg, int* __restrict__ bsum, int N)
{
    __shared__ int s[256];
    int t = threadIdx.x;
    int i = blockIdx.x * 256 + t;
    s[t] = (i < N) ? deg[i] : 0;
    __syncthreads();
    #pragma unroll
    for (int o = 128; o > 0; o >>= 1) {
        if (t < o) s[t] += s[t + o];
        __syncthreads();
    }
    if (t == 0) bsum[blockIdx.x] = s[0];
}

__global__ __launch_bounds__(512) void k_scan_bsum(
    const int* __restrict__ bsum, int* __restrict__ bexc, int NB)
{
    __shared__ int s[512];
    int t = threadIdx.x;
    s[t] = (t < NB) ? bsum[t] : 0;
    __syncthreads();
    for (int o = 1; o < 512; o <<= 1) {
        int v = (t >= o) ? s[t - o] : 0;
        __syncthreads();
        s[t] += v;
        __syncthreads();
    }
    if (t < NB) bexc[t] = (t == 0) ? 0 : s[t - 1];
}

__global__ __launch_bounds__(256) void k_rowptr(
    const int* __restrict__ deg, const int* __restrict__ bexc,
    int* __restrict__ rowptr, int N, int Etot)
{
    __shared__ int s[256];
    int t = threadIdx.x;
    int i = blockIdx.x * 256 + t;
    int v = (i < N) ? deg[i] : 0;
    s[t] = v;
    __syncthreads();
    for (int o = 1; o < 256; o <<= 1) {
        int u = (t >= o) ? s[t - o] : 0;
        __syncthreads();
        s[t] += u;
        __syncthreads();
    }
    if (i < N) rowptr[i] = bexc[blockIdx.x] + s[t] - v;  // exclusive
    if (i == 0) rowptr[N] = Etot;
}

__global__ __launch_bounds__(256) void k_fill(
    const int* __restrict__ src, const int* __restrict__ dst,
    const int* __restrict__ rank, const int* __restrict__ rowptr,
    int* __restrict__ csr, long E)
{
    long i = (long)blockIdx.x * 256 + threadIdx.x;
    if (i >= E) return;
    csr[rowptr[dst[i]] + rank[i]] = src[i];
}

// ---------------- K-gather1 v4: wave per dst, 8-edge chunks, pipelined -------
// Phase 1 (lane = e*8+h): 64 distinct exp-weights per issue.
// Phase 2 (lane = half*32+p): bf16x2 channel gathers, w/s via shfl.
// Chunk i+1's csr load + a_src gather are issued BEFORE chunk i's phase 2 so
// their latency overlaps phase-2's gathers (the loop was latency-chain bound).
__global__ __launch_bounds__(256) void k_gather1(
    const int* __restrict__ rowptr, const int* __restrict__ csr,
    const ushort* __restrict__ h1b, const float* __restrict__ a_src,
    const float* __restrict__ a_dst, float* __restrict__ agg, int N)
{
    const uint* __restrict__ h1u = (const uint*)h1b;
    int wave = threadIdx.x >> 6, lane = threadIdx.x & 63;
    int d = blockIdx.x * 4 + wave;
    if (d >= N) return;

    int e    = lane >> 3;        // edge slot (phase 1)
    int h    = lane & 7;         // head (phase 1)
    int p    = lane & 31;        // channel pair (phase 2): channels 2p,2p+1
    int half = lane >> 5;        // half-wave (phase 2)
    int hp   = p >> 2;           // head of channel 2p
    int e2b  = half * 4;         // this half's first edge slot

    float adst = a_dst[d * NH + h];

    // self-loop
    float ws = __expf(lrelu(a_src[d * NH + h] + adst));
    float wsum = (e == 0) ? ws : 0.f;
    float w2s = __shfl(ws, hp, 64);          // lane hp holds head hp
    uint u0 = h1u[(size_t)d * 32 + p];
    float wini = (half == 0) ? w2s : 0.f;
    float accx = wini * __uint_as_float(u0 << 16);
    float accy = wini * __uint_as_float(u0 & 0xFFFF0000u);

    int jb = rowptr[d], je = rowptr[d + 1];

    // pipeline prologue: chunk 0's csr + a_src
    int  idx0   = jb + e;
    bool v_cur  = idx0 < je;
    int  sl_cur = v_cur ? csr[idx0] : d;
    float as_cur = a_src[sl_cur * NH + h];

    for (int j0 = jb; j0 < je; j0 += 8) {
        // prefetch chunk i+1 (independent of current phase 2)
        int  idxn  = j0 + 8 + e;
        bool v_n   = idxn < je;
        int  sl_n  = v_n ? csr[idxn] : d;
        float as_n = a_src[sl_n * NH + h];

        // phase 1: weights for current 8 edges
        float w = v_cur ? __expf(lrelu(as_cur + adst)) : 0.f;
        wsum += w;
        int sl = sl_cur;

        // phase 2: accumulate 4 edges per half-wave
        #pragma unroll
        for (int k = 0; k < 4; ++k) {
            int es = e2b + k;
            int   s2 = __shfl(sl, es * 8, 64);
            float w2 = __shfl(w, es * 8 + hp, 64);
            uint  u  = h1u[(size_t)s2 * 32 + p];
            accx += w2 * __uint_as_float(u << 16);
            accy += w2 * __uint_as_float(u & 0xFFFF0000u);
        }

        sl_cur = sl_n; as_cur = as_n; v_cur = v_n;
    }

    // reduce wsum over edge slots (lanes sharing h)
    wsum += __shfl_xor(wsum, 8, 64);
    wsum += __shfl_xor(wsum, 16, 64);
    wsum += __shfl_xor(wsum, 32, 64);
    float winv = 1.f / (__shfl(wsum, hp, 64) + 1e-16f);

    // merge the two halves' edge subsets
    accx += __shfl_xor(accx, 32, 64);
    accy += __shfl_xor(accy, 32, 64);
    if (half == 0) {
        ((float2*)agg)[(size_t)d * 32 + p] = make_float2(accx * winv, accy * winv);
    }
}

// ------- K4: emb = agg1+b1 (OUT0); x2 = elu(emb); h2p = x2@W2; a_*2 ----------
__global__ __launch_bounds__(256) void k_node2(
    const float* __restrict__ agg1, const float* __restrict__ b1,
    const float* __restrict__ W2, const float* __restrict__ att_s2,
    const float* __restrict__ att_d2, float* __restrict__ emb_out,
    float* __restrict__ h2p, float* __restrict__ a_src2, float* __restrict__ a_dst2,
    int N)
{
    __shared__ float sW[HD * NC];
    __shared__ float sb[HD];
    __shared__ float sas[NC], sad[NC];
    int t = threadIdx.x;
    for (int i = t; i < HD * NC; i += 256) sW[i] = W2[i];
    if (t < HD) sb[t] = b1[t];
    if (t < NC) { sas[t] = att_s2[t]; sad[t] = att_d2[t]; }
    __syncthreads();
    int n = blockIdx.x * 256 + t;
    if (n >= N) return;
    const float* ag = agg1 + (size_t)n * HD;
    float* eo = emb_out + (size_t)n * HD;
    float acc[NC];
    #pragma unroll
    for (int c = 0; c < NC; ++c) acc[c] = 0.f;
    #pragma unroll 8
    for (int k = 0; k < HD; ++k) {
        float v = ag[k] + sb[k];
        eo[k] = v;
        float xv = v > 0.f ? v : expm1f(v);   // jax.nn.elu
        #pragma unroll
        for (int c = 0; c < NC; ++c) acc[c] += xv * sW[k * NC + c];
    }
    float as = 0.f, ad = 0.f;
    float* hp = h2p + (size_t)n * 8;
    #pragma unroll
    for (int c = 0; c < NC; ++c) {
        hp[c] = acc[c];
        as += acc[c] * sas[c];
        ad += acc[c] * sad[c];
    }
    hp[7] = 0.f;
    a_src2[n] = as;
    a_dst2[n] = ad;
}

// ------- K-gather2: WAVE per dst; lane = edge-slot*8 + channel; pipelined ----
__global__ __launch_bounds__(256) void k_gather2(
    const int* __restrict__ rowptr, const int* __restrict__ csr,
    const float* __restrict__ h2p, const float* __restrict__ a_src2,
    const float* __restrict__ a_dst2, const float* __restrict__ b2,
    float* __restrict__ out, int N)
{
    int t = threadIdx.x;
    int wave = t >> 6, lane = t & 63;
    int g = lane >> 3;           // edge slot 0..7
    int c = lane & 7;            // channel (7 = pad)
    int n = blockIdx.x * 4 + wave;
    if (n >= N) return;
    float ad = a_dst2[n];
    float w = __expf(lrelu(a_src2[n] + ad));   // self-loop
    float acc  = (g == 0) ? w * h2p[(size_t)n * 8 + c] : 0.f;
    float wsum = (g == 0) ? w : 0.f;
    int jb = rowptr[n], je = rowptr[n + 1];

    // pipeline prologue
    int  idx0  = jb + g;
    bool v_cur = idx0 < je;
    int  s_cur = v_cur ? csr[idx0] : n;

    for (int j = jb; j < je; j += 8) {
        int  idxn  = j + 8 + g;
        bool v_n   = idxn < je;
        int  s_n   = v_n ? csr[idxn] : n;
        // a_src2 + h2p gathers both depend only on s_cur (loaded last iter)
        float ww = v_cur ? __expf(lrelu(a_src2[s_cur] + ad)) : 0.f;
        acc += ww * h2p[(size_t)s_cur * 8 + c];
        wsum += ww;
        s_cur = s_n; v_cur = v_n;
    }
    #pragma unroll
    for (int o = 32; o >= 8; o >>= 1) {
        acc  += __shfl_xor(acc, o, 64);
        wsum += __shfl_xor(wsum, o, 64);
    }
    float l = (c < NC) ? (acc / (wsum + 1e-16f) + b2[c]) : -1e30f;
    float m = l;
    #pragma unroll
    for (int o = 4; o > 0; o >>= 1) m = fmaxf(m, __shfl_xor(m, o, 8));
    float ex = (c < NC) ? __expf(l - m) : 0.f;
    float s8 = ex;
    #pragma unroll
    for (int o = 4; o > 0; o >>= 1) s8 += __shfl_xor(s8, o, 8);
    if (g == 0 && c < NC) out[(size_t)n * NC + c] = l - m - logf(s8);
}

extern "C" void kernel_launch(void* const* d_in, const int* in_sizes, int n_in,
                              void* d_out, int out_size, void* d_ws, size_t ws_size,
                              hipStream_t stream)
{
    const float* x       = (const float*)d_in[0];
    const int*   ei      = (const int*)d_in[1];
    const float* W1      = (const float*)d_in[2];
    const float* att_s1  = (const float*)d_in[3];
    const float* att_d1  = (const float*)d_in[4];
    const float* b1      = (const float*)d_in[5];
    const float* W2      = (const float*)d_in[6];
    const float* att_s2  = (const float*)d_in[7];
    const float* att_d2  = (const float*)d_in[8];
    const float* b2      = (const float*)d_in[9];

    const int  N = in_sizes[0] / F_IN;
    const long E = (long)in_sizes[1] / 2;
    const int* src = ei;
    const int* dst = ei + E;

    const int Npad  = (N + 3) & ~3;
    const int Np1p  = (N + 4) & ~3;
    const long Epad = (E + 3) & ~3;

    // ---- workspace layout ----
    int* deg    = (int*)d_ws;                 // Npad   (zeroed)
    int* rowptr = deg + Npad;                 // N+1
    int* bexc   = rowptr + Np1p;              // 512
    int* bsum   = bexc + 512;                 // 512
    int* csr    = bsum + 512;                 // E
    ushort* h1b   = (ushort*)(csr + Epad);    // Npad*64 bf16
    float* a_src1 = (float*)(h1b + (size_t)Npad * HD); // N*8
    float* a_dst1 = a_src1 + (size_t)N * NH;  // N*8
    float* agg1   = a_dst1 + (size_t)N * NH;  // N*64
    float* h2p    = agg1 + (size_t)N * HD;    // N*8 (padded NC->8)
    float* a_src2 = h2p + (size_t)N * 8;      // Npad
    float* a_dst2 = a_src2 + Npad;            // Npad
    float* wsend  = a_dst2 + Npad;
    // rank[E] aliases agg1's space (dead before k_gather1 writes agg1)
    int* rank = (E <= (long)N * HD) ? (int*)agg1 : (int*)wsend;

    hipMemsetAsync(deg, 0, (size_t)Npad * sizeof(int), stream);

    const int NB = (N + 255) / 256;
    dim3 b256(256);

    k_gemm1<<<dim3((N + 63) / 64), b256, 0, stream>>>(x, W1, att_s1, att_d1,
                                                      h1b, a_src1, a_dst1, N);
    // CSR build
    k_hist<<<dim3((unsigned)((E + 255) / 256)), b256, 0, stream>>>(dst, deg, rank, E);
    k_bsum<<<dim3(NB), b256, 0, stream>>>(deg, bsum, N);
    k_scan_bsum<<<dim3(1), dim3(512), 0, stream>>>(bsum, bexc, NB);
    k_rowptr<<<dim3(NB), b256, 0, stream>>>(deg, bexc, rowptr, N, (int)E);
    k_fill<<<dim3((unsigned)((E + 255) / 256)), b256, 0, stream>>>(
        src, dst, rank, rowptr, csr, E);

    // Layer 1 aggregate
    k_gather1<<<dim3((N + 3) / 4), b256, 0, stream>>>(
        rowptr, csr, h1b, a_src1, a_dst1, agg1, N);

    // emb output + layer-2 prologue
    float* emb = (float*)d_out;               // N*64
    float* lsm = emb + (size_t)N * HD;        // N*7
    k_node2<<<dim3(NB), b256, 0, stream>>>(
        agg1, b1, W2, att_s2, att_d2, emb, h2p, a_src2, a_dst2, N);

    // Layer 2 aggregate + fused log_softmax
    k_gather2<<<dim3((N + 3) / 4), b256, 0, stream>>>(
        rowptr, csr, h2p, a_src2, a_dst2, b2, lsm, N);
}

// Round 7
// 713.427 us; speedup vs baseline: 12.3723x; 1.0320x over previous
//
#include <hip/hip_runtime.h>
#include <hip/hip_bf16.h>
#include <math.h>

#define F_IN 128
#define HD   64    // H*D layer1
#define NH   8
#define DH   8
#define NC   7     // classes

__device__ __forceinline__ float lrelu(float e) { return fmaxf(e, 0.2f * e); }
__device__ __forceinline__ ushort f2bf(float f) {
    unsigned u = __float_as_uint(f);
    unsigned rounded = u + 0x7FFF + ((u >> 16) & 1);
    return (ushort)(rounded >> 16);
}

// ---------- K1 fused: gemm1 (bid%3==0) + hist (else) -------------------------
// gemm: h1b = bf16(x@W1), a_src1/a_dst1; hist: deg/rank build. Independent
// work fused so hist's atomic latency hides under gemm's FMA/LDS work.
__global__ __launch_bounds__(256) void k_gemm1h(
    const float* __restrict__ x, const float* __restrict__ W1,
    const float* __restrict__ att_src, const float* __restrict__ att_dst,
    ushort* __restrict__ h1b, float* __restrict__ a_src, float* __restrict__ a_dst,
    int N, int GB,
    const int* __restrict__ dstArr, int* __restrict__ deg, int* __restrict__ rank,
    long E)
{
    __shared__ float sW[F_IN * HD];      // 32 KB
    __shared__ float sAs[HD], sAd[HD];
    int t = threadIdx.x;
    int bid = blockIdx.x;

    if (bid % 3 != 0) {
        // ---- hist branch: grid-stride over edges ----
        long hb = (long)(bid / 3) * 2 + (bid % 3) - 1;    // [0, 2*GB)
        long stride = (long)(2 * GB) * 256;
        for (long i = hb * 256 + t; i < E; i += stride)
            rank[i] = atomicAdd(&deg[dstArr[i]], 1);
        return;
    }

    int gb = bid / 3;                                     // [0, GB)
    for (int i = t; i < F_IN * HD; i += 256) sW[i] = W1[i];
    if (t < HD) { sAs[t] = att_src[t]; sAd[t] = att_dst[t]; }
    __syncthreads();

    int lane = t & 63;
    int wave = t >> 6;
    int base = gb * 64 + wave * 16;

    for (int it = 0; it < 2; ++it) {
        int r0 = base + it * 8;
        if (r0 >= N) break;
        int nr = N - r0; if (nr > 8) nr = 8;
        float acc[8];
        #pragma unroll
        for (int r = 0; r < 8; ++r) acc[r] = 0.f;

        if (nr == 8) {
            for (int k4 = 0; k4 < F_IN / 4; ++k4) {
                float4 xv[8];
                #pragma unroll
                for (int r = 0; r < 8; ++r)
                    xv[r] = *(const float4*)(x + (size_t)(r0 + r) * F_IN + k4 * 4);
                #pragma unroll
                for (int kk = 0; kk < 4; ++kk) {
                    float sw = sW[(k4 * 4 + kk) * HD + lane];
                    acc[0] += ((const float*)&xv[0])[kk] * sw;
                    acc[1] += ((const float*)&xv[1])[kk] * sw;
                    acc[2] += ((const float*)&xv[2])[kk] * sw;
                    acc[3] += ((const float*)&xv[3])[kk] * sw;
                    acc[4] += ((const float*)&xv[4])[kk] * sw;
                    acc[5] += ((const float*)&xv[5])[kk] * sw;
                    acc[6] += ((const float*)&xv[6])[kk] * sw;
                    acc[7] += ((const float*)&xv[7])[kk] * sw;
                }
            }
        } else {
            #pragma unroll
            for (int r = 0; r < 8; ++r) {
                if (r < nr) {
                    const float4* xr4 = (const float4*)(x + (size_t)(r0 + r) * F_IN);
                    float a = 0.f;
                    for (int k4 = 0; k4 < F_IN / 4; ++k4) {
                        float4 q = xr4[k4];
                        a += q.x * sW[(k4 * 4 + 0) * HD + lane];
                        a += q.y * sW[(k4 * 4 + 1) * HD + lane];
                        a += q.z * sW[(k4 * 4 + 2) * HD + lane];
                        a += q.w * sW[(k4 * 4 + 3) * HD + lane];
                    }
                    acc[r] = a;
                }
            }
        }
        #pragma unroll
        for (int r = 0; r < 8; ++r) {
            if (r < nr) {
                int row = r0 + r;
                float a = acc[r];
                h1b[(size_t)row * HD + lane] = f2bf(a);
                float vs = a * sAs[lane];
                float vd = a * sAd[lane];
                #pragma unroll
                for (int o = 4; o > 0; o >>= 1) {
                    vs += __shfl_down(vs, o, 8);
                    vd += __shfl_down(vd, o, 8);
                }
                if ((lane & 7) == 0) {
                    int h = lane >> 3;
                    a_src[row * NH + h] = vs;
                    a_dst[row * NH + h] = vd;
                }
            }
        }
    }
}

// ---------------- CSR build (rest) --------------------------------------------
__global__ __launch_bounds__(256) void k_bsum(
    const int* __restrict__ deg, int* __restrict__ bsum, int N)
{
    __shared__ int s[256];
    int t = threadIdx.x;
    int i = blockIdx.x * 256 + t;
    s[t] = (i < N) ? deg[i] : 0;
    __syncthreads();
    #pragma unroll
    for (int o = 128; o > 0; o >>= 1) {
        if (t < o) s[t] += s[t + o];
        __syncthreads();
    }
    if (t == 0) bsum[blockIdx.x] = s[0];
}

__global__ __launch_bounds__(512) void k_scan_bsum(
    const int* __restrict__ bsum, int* __restrict__ bexc, int NB)
{
    __shared__ int s[512];
    int t = threadIdx.x;
    s[t] = (t < NB) ? bsum[t] : 0;
    __syncthreads();
    for (int o = 1; o < 512; o <<= 1) {
        int v = (t >= o) ? s[t - o] : 0;
        __syncthreads();
        s[t] += v;
        __syncthreads();
    }
    if (t < NB) bexc[t] = (t == 0) ? 0 : s[t - 1];
}

__global__ __launch_bounds__(256) void k_rowptr(
    const int* __restrict__ deg, const int* __restrict__ bexc,
    int* __restrict__ rowptr, int N, int Etot)
{
    __shared__ int s[256];
    int t = threadIdx.x;
    int i = blockIdx.x * 256 + t;
    int v = (i < N) ? deg[i] : 0;
    s[t] = v;
    __syncthreads();
    for (int o = 1; o < 256; o <<= 1) {
        int u = (t >= o) ? s[t - o] : 0;
        __syncthreads();
        s[t] += u;
        __syncthreads();
    }
    if (i < N) rowptr[i] = bexc[blockIdx.x] + s[t] - v;  // exclusive
    if (i == 0) rowptr[N] = Etot;
}

__global__ __launch_bounds__(256) void k_fill(
    const int* __restrict__ src, const int* __restrict__ dst,
    const int* __restrict__ rank, const int* __restrict__ rowptr,
    int* __restrict__ csr, long E)
{
    long i = (long)blockIdx.x * 256 + threadIdx.x;
    if (i >= E) return;
    csr[rowptr[dst[i]] + rank[i]] = src[i];
}

// ---------------- K-gather1 v5: wave per dst, lane=(e,h), NO loop shuffles ---
// Head h owns dwords h*4..h*4+3 of the 32-dword bf16 row, so lane (e,h) loads
// its edge's 4 consecutive dwords (merged to one dwordx4: 64 lanes = 8 full
// rows) and scales by its OWN weight. Per 8-edge chunk: 3 VMEM + ~27 VALU,
// zero LDS ops (R5 version: 6 VMEM + ~55 VALU + 8 ds_bpermute).
// Reduction over edge slots happens once per row in the epilogue.
__global__ __launch_bounds__(256) void k_gather1(
    const int* __restrict__ rowptr, const int* __restrict__ csr,
    const ushort* __restrict__ h1b, const float* __restrict__ a_src,
    const float* __restrict__ a_dst, float* __restrict__ agg, int N)
{
    const uint* __restrict__ h1u = (const uint*)h1b;
    int wave = threadIdx.x >> 6, lane = threadIdx.x & 63;
    int d = blockIdx.x * 4 + wave;
    if (d >= N) return;
    int e = lane >> 3;           // edge slot
    int h = lane & 7;            // head; channels 8h..8h+7 = dwords 4h..4h+3

    float adst = a_dst[d * NH + h];
    float ws = __expf(lrelu(a_src[d * NH + h] + adst));   // self-loop weight
    float wsum = (e == 0) ? ws : 0.f;

    float ax0 = 0.f, ay0 = 0.f, ax1 = 0.f, ay1 = 0.f;
    float ax2 = 0.f, ay2 = 0.f, ax3 = 0.f, ay3 = 0.f;
    if (e == 0) {
        size_t b = (size_t)d * 32 + h * 4;
        uint u0 = h1u[b], u1 = h1u[b + 1], u2 = h1u[b + 2], u3 = h1u[b + 3];
        ax0 = ws * __uint_as_float(u0 << 16); ay0 = ws * __uint_as_float(u0 & 0xFFFF0000u);
        ax1 = ws * __uint_as_float(u1 << 16); ay1 = ws * __uint_as_float(u1 & 0xFFFF0000u);
        ax2 = ws * __uint_as_float(u2 << 16); ay2 = ws * __uint_as_float(u2 & 0xFFFF0000u);
        ax3 = ws * __uint_as_float(u3 << 16); ay3 = ws * __uint_as_float(u3 & 0xFFFF0000u);
    }

    int jb = rowptr[d], je = rowptr[d + 1];
    // software pipeline: next chunk's csr + a_src prefetched during accumulate
    int  idx0   = jb + e;
    bool v_cur  = idx0 < je;
    int  sl_cur = v_cur ? csr[idx0] : d;
    float as_cur = a_src[sl_cur * NH + h];

    for (int j0 = jb; j0 < je; j0 += 8) {
        int  idxn  = j0 + 8 + e;
        bool v_n   = idxn < je;
        int  sl_n  = v_n ? csr[idxn] : d;
        float as_n = a_src[sl_n * NH + h];

        float w = v_cur ? __expf(lrelu(as_cur + adst)) : 0.f;
        wsum += w;
        size_t b = (size_t)sl_cur * 32 + h * 4;
        uint u0 = h1u[b], u1 = h1u[b + 1], u2 = h1u[b + 2], u3 = h1u[b + 3];
        ax0 += w * __uint_as_float(u0 << 16); ay0 += w * __uint_as_float(u0 & 0xFFFF0000u);
        ax1 += w * __uint_as_float(u1 << 16); ay1 += w * __uint_as_float(u1 & 0xFFFF0000u);
        ax2 += w * __uint_as_float(u2 << 16); ay2 += w * __uint_as_float(u2 & 0xFFFF0000u);
        ax3 += w * __uint_as_float(u3 << 16); ay3 += w * __uint_as_float(u3 & 0xFFFF0000u);

        sl_cur = sl_n; as_cur = as_n; v_cur = v_n;
    }

    // epilogue: reduce over edge slots (xor bits 3..5 keeps h fixed)
    #pragma unroll
    for (int o = 8; o <= 32; o <<= 1) {
        wsum += __shfl_xor(wsum, o, 64);
        ax0 += __shfl_xor(ax0, o, 64); ay0 += __shfl_xor(ay0, o, 64);
        ax1 += __shfl_xor(ax1, o, 64); ay1 += __shfl_xor(ay1, o, 64);
        ax2 += __shfl_xor(ax2, o, 64); ay2 += __shfl_xor(ay2, o, 64);
        ax3 += __shfl_xor(ax3, o, 64); ay3 += __shfl_xor(ay3, o, 64);
    }
    if (e == 0) {
        float winv = 1.f / (wsum + 1e-16f);
        float* op = agg + (size_t)d * HD + h * 8;
        *(float4*)(op)     = make_float4(ax0 * winv, ay0 * winv, ax1 * winv, ay1 * winv);
        *(float4*)(op + 4) = make_float4(ax2 * winv, ay2 * winv, ax3 * winv, ay3 * winv);
    }
}

// ------- K4: emb = agg1+b1 (OUT0); x2 = elu(emb); h2p = x2@W2; a_*2 ----------
__global__ __launch_bounds__(256) void k_node2(
    const float* __restrict__ agg1, const float* __restrict__ b1,
    const float* __restrict__ W2, const float* __restrict__ att_s2,
    const float* __restrict__ att_d2, float* __restrict__ emb_out,
    float* __restrict__ h2p, float* __restrict__ a_src2, float* __restrict__ a_dst2,
    int N)
{
    __shared__ float sW[HD * NC];
    __shared__ float sb[HD];
    __shared__ float sas[NC], sad[NC];
    int t = threadIdx.x;
    for (int i = t; i < HD * NC; i += 256) sW[i] = W2[i];
    if (t < HD) sb[t] = b1[t];
    if (t < NC) { sas[t] = att_s2[t]; sad[t] = att_d2[t]; }
    __syncthreads();
    int n = blockIdx.x * 256 + t;
    if (n >= N) return;
    const float* ag = agg1 + (size_t)n * HD;
    float* eo = emb_out + (size_t)n * HD;
    float acc[NC];
    #pragma unroll
    for (int c = 0; c < NC; ++c) acc[c] = 0.f;
    #pragma unroll 8
    for (int k = 0; k < HD; ++k) {
        float v = ag[k] + sb[k];
        eo[k] = v;
        float xv = v > 0.f ? v : expm1f(v);   // jax.nn.elu
        #pragma unroll
        for (int c = 0; c < NC; ++c) acc[c] += xv * sW[k * NC + c];
    }
    float as = 0.f, ad = 0.f;
    float* hp = h2p + (size_t)n * 8;
    #pragma unroll
    for (int c = 0; c < NC; ++c) {
        hp[c] = acc[c];
        as += acc[c] * sas[c];
        ad += acc[c] * sad[c];
    }
    hp[7] = 0.f;
    a_src2[n] = as;
    a_dst2[n] = ad;
}

// ------- K-gather2: WAVE per dst; lane = edge-slot*8 + channel; pipelined ----
__global__ __launch_bounds__(256) void k_gather2(
    const int* __restrict__ rowptr, const int* __restrict__ csr,
    const float* __restrict__ h2p, const float* __restrict__ a_src2,
    const float* __restrict__ a_dst2, const float* __restrict__ b2,
    float* __restrict__ out, int N)
{
    int t = threadIdx.x;
    int wave = t >> 6, lane = t & 63;
    int g = lane >> 3;           // edge slot 0..7
    int c = lane & 7;            // channel (7 = pad)
    int n = blockIdx.x * 4 + wave;
    if (n >= N) return;
    float ad = a_dst2[n];
    float w = __expf(lrelu(a_src2[n] + ad));   // self-loop
    float acc  = (g == 0) ? w * h2p[(size_t)n * 8 + c] : 0.f;
    float wsum = (g == 0) ? w : 0.f;
    int jb = rowptr[n], je = rowptr[n + 1];

    int  idx0  = jb + g;
    bool v_cur = idx0 < je;
    int  s_cur = v_cur ? csr[idx0] : n;

    for (int j = jb; j < je; j += 8) {
        int  idxn  = j + 8 + g;
        bool v_n   = idxn < je;
        int  s_n   = v_n ? csr[idxn] : n;
        float ww = v_cur ? __expf(lrelu(a_src2[s_cur] + ad)) : 0.f;
        acc += ww * h2p[(size_t)s_cur * 8 + c];
        wsum += ww;
        s_cur = s_n; v_cur = v_n;
    }
    #pragma unroll
    for (int o = 32; o >= 8; o >>= 1) {
        acc  += __shfl_xor(acc, o, 64);
        wsum += __shfl_xor(wsum, o, 64);
    }
    float l = (c < NC) ? (acc / (wsum + 1e-16f) + b2[c]) : -1e30f;
    float m = l;
    #pragma unroll
    for (int o = 4; o > 0; o >>= 1) m = fmaxf(m, __shfl_xor(m, o, 8));
    float ex = (c < NC) ? __expf(l - m) : 0.f;
    float s8 = ex;
    #pragma unroll
    for (int o = 4; o > 0; o >>= 1) s8 += __shfl_xor(s8, o, 8);
    if (g == 0 && c < NC) out[(size_t)n * NC + c] = l - m - logf(s8);
}

extern "C" void kernel_launch(void* const* d_in, const int* in_sizes, int n_in,
                              void* d_out, int out_size, void* d_ws, size_t ws_size,
                              hipStream_t stream)
{
    const float* x       = (const float*)d_in[0];
    const int*   ei      = (const int*)d_in[1];
    const float* W1      = (const float*)d_in[2];
    const float* att_s1  = (const float*)d_in[3];
    const float* att_d1  = (const float*)d_in[4];
    const float* b1      = (const float*)d_in[5];
    const float* W2      = (const float*)d_in[6];
    const float* att_s2  = (const float*)d_in[7];
    const float* att_d2  = (const float*)d_in[8];
    const float* b2      = (const float*)d_in[9];

    const int  N = in_sizes[0] / F_IN;
    const long E = (long)in_sizes[1] / 2;
    const int* src = ei;
    const int* dst = ei + E;

    const int Npad  = (N + 3) & ~3;
    const int Np1p  = (N + 4) & ~3;
    const long Epad = (E + 3) & ~3;

    // ---- workspace layout ----
    int* deg    = (int*)d_ws;                 // Npad   (zeroed)
    int* rowptr = deg + Npad;                 // N+1
    int* bexc   = rowptr + Np1p;              // 512
    int* bsum   = bexc + 512;                 // 512
    int* csr    = bsum + 512;                 // E
    ushort* h1b   = (ushort*)(csr + Epad);    // Npad*64 bf16
    float* a_src1 = (float*)(h1b + (size_t)Npad * HD); // N*8
    float* a_dst1 = a_src1 + (size_t)N * NH;  // N*8
    float* agg1   = a_dst1 + (size_t)N * NH;  // N*64
    float* h2p    = agg1 + (size_t)N * HD;    // N*8 (padded NC->8)
    float* a_src2 = h2p + (size_t)N * 8;      // Npad
    float* a_dst2 = a_src2 + Npad;            // Npad
    float* wsend  = a_dst2 + Npad;
    // rank[E] aliases agg1's space (dead before k_gather1 writes agg1)
    int* rank = (E <= (long)N * HD) ? (int*)agg1 : (int*)wsend;

    hipMemsetAsync(deg, 0, (size_t)Npad * sizeof(int), stream);

    const int NB = (N + 255) / 256;
    const int GB = (N + 63) / 64;
    dim3 b256(256);

    // fused node transform + degree histogram (independent work)
    k_gemm1h<<<dim3(3 * GB), b256, 0, stream>>>(
        x, W1, att_s1, att_d1, h1b, a_src1, a_dst1, N, GB,
        dst, deg, rank, E);
    // CSR build (rest)
    k_bsum<<<dim3(NB), b256, 0, stream>>>(deg, bsum, N);
    k_scan_bsum<<<dim3(1), dim3(512), 0, stream>>>(bsum, bexc, NB);
    k_rowptr<<<dim3(NB), b256, 0, stream>>>(deg, bexc, rowptr, N, (int)E);
    k_fill<<<dim3((unsigned)((E + 255) / 256)), b256, 0, stream>>>(
        src, dst, rank, rowptr, csr, E);

    // Layer 1 aggregate
    k_gather1<<<dim3((N + 3) / 4), b256, 0, stream>>>(
        rowptr, csr, h1b, a_src1, a_dst1, agg1, N);

    // emb output + layer-2 prologue
    float* emb = (float*)d_out;               // N*64
    float* lsm = emb + (size_t)N * HD;        // N*7
    k_node2<<<dim3(NB), b256, 0, stream>>>(
        agg1, b1, W2, att_s2, att_d2, emb, h2p, a_src2, a_dst2, N);

    // Layer 2 aggregate + fused log_softmax
    k_gather2<<<dim3((N + 3) / 4), b256, 0, stream>>>(
        rowptr, csr, h2p, a_src2, a_dst2, b2, lsm, N);
}